// Round 3
// baseline (811.789 us; speedup 1.0000x reference)
//
#include <hip/hip_runtime.h>
#include <math.h>

#define N_NODES 50000
#define D 160
#define H 5
#define C 32
#define HC 160
#define E_EDGES 800000
#define ED 16
#define HID 512
#define EPS 1e-5f
#define NEG_SLOPE 0.2f

typedef __attribute__((ext_vector_type(8))) short bf16x8;
typedef __attribute__((ext_vector_type(4))) float f32x4;
typedef __attribute__((ext_vector_type(4))) short short4v;

__device__ inline float bf2f(short s) {
  unsigned u = ((unsigned)(unsigned short)s) << 16;
  return __builtin_bit_cast(float, u);
}
__device__ inline short f2bf(float f) {
  unsigned u = __builtin_bit_cast(unsigned, f);
  u = u + 0x7fffu + ((u >> 16) & 1u);
  return (short)(u >> 16);
}
__device__ inline float selu_f(float v) {
  return 1.0507009873554805f * (v > 0.f ? v : 1.6732632423543772f * (__expf(v) - 1.f));
}

// ---------------- weight prep: transpose + bf16 (+ padded WeT) ----------------
__global__ void prep_weights(const float* __restrict__ Wl, const float* __restrict__ Wr,
                             const float* __restrict__ Wm1, const float* __restrict__ Wm2,
                             const float* __restrict__ We,
                             short* __restrict__ WlT, short* __restrict__ WrT,
                             short* __restrict__ W1T, short* __restrict__ W2T,
                             short* __restrict__ WeTp) {
  int i = blockIdx.x * blockDim.x + threadIdx.x;
  if (i < 25600) { int n = i / 160, k = i % 160; WlT[n*160 + k] = f2bf(Wl[k*160 + n]); return; }
  i -= 25600;
  if (i < 25600) { int n = i / 160, k = i % 160; WrT[n*160 + k] = f2bf(Wr[k*160 + n]); return; }
  i -= 25600;
  if (i < 81920) { int n = i / 160, k = i % 160; W1T[n*160 + k] = f2bf(Wm1[k*512 + n]); return; }
  i -= 81920;
  if (i < 81920) { int n = i / 512, k = i % 512; W2T[n*512 + k] = f2bf(Wm2[k*160 + n]); return; }
  i -= 81920;
  if (i < 5120) { int col = i / 32, k = i % 32;
    WeTp[col*32 + k] = (k < ED) ? f2bf(We[k*160 + col]) : (short)0; }
}

// ---------------- convert x to bf16 ----------------
__global__ void convert_x(const float* __restrict__ x, short* __restrict__ xb) {
  int i = blockIdx.x * blockDim.x + threadIdx.x;
  if (i < N_NODES * D / 8) {
    const float4* s = (const float4*)(x + (size_t)i * 8);
    float4 a = s[0], b = s[1];
    bf16x8 o;
    o[0] = f2bf(a.x); o[1] = f2bf(a.y); o[2] = f2bf(a.z); o[3] = f2bf(a.w);
    o[4] = f2bf(b.x); o[5] = f2bf(b.y); o[6] = f2bf(b.z); o[7] = f2bf(b.w);
    *(bf16x8*)(xb + (size_t)i * 8) = o;
  }
}

// ---------------- proj MFMA: xl = x@Wl+bl, xr = x@Wr+br (bf16 out) ----------------
__global__ __launch_bounds__(256) void proj_mfma(
    const short* __restrict__ xb, const short* __restrict__ WlT, const short* __restrict__ WrT,
    const float* __restrict__ bl, const float* __restrict__ br,
    short* __restrict__ xl, short* __restrict__ xr)
{
  __shared__ short As[64][40];
  int t = threadIdx.x;
  int wave = t >> 6, lane = t & 63;
  int lq = lane >> 4, lc = lane & 15;
  int row0 = blockIdx.x * 64;
  f32x4 accl[10] = {}, accr[10] = {};
  for (int kt = 0; kt < 5; ++kt) {
    int k0 = kt * 32;
    {
      int r = t >> 2, seg = t & 3;
      int gr = min(row0 + r, N_NODES - 1);
      bf16x8 v = *(const bf16x8*)&xb[(size_t)gr * 160 + k0 + seg * 8];
      *(bf16x8*)&As[r][seg * 8] = v;
    }
    __syncthreads();
    bf16x8 af = *(bf16x8*)&As[wave * 16 + lc][lq * 8];
#pragma unroll
    for (int ct = 0; ct < 10; ++ct) {
      int cc = ct * 16 + lc;
      bf16x8 bfl = *(const bf16x8*)&WlT[cc * 160 + k0 + lq * 8];
      accl[ct] = __builtin_amdgcn_mfma_f32_16x16x32_bf16(af, bfl, accl[ct], 0, 0, 0);
      bf16x8 bfr = *(const bf16x8*)&WrT[cc * 160 + k0 + lq * 8];
      accr[ct] = __builtin_amdgcn_mfma_f32_16x16x32_bf16(af, bfr, accr[ct], 0, 0, 0);
    }
    __syncthreads();
  }
#pragma unroll
  for (int ct = 0; ct < 10; ++ct) {
    int col = ct * 16 + lc;
    float bbl = bl[col], bbr = br[col];
#pragma unroll
    for (int rg = 0; rg < 4; ++rg) {
      int row = row0 + wave * 16 + lq * 4 + rg;
      if (row < N_NODES) {
        xl[(size_t)row * 160 + col] = f2bf(accl[ct][rg] + bbl);
        xr[(size_t)row * 160 + col] = f2bf(accr[ct][rg] + bbr);
      }
    }
  }
}

// ---------------- CSR build ----------------
__global__ void count_kernel(const int* __restrict__ ei, int* __restrict__ cnt) {
  int e = blockIdx.x * blockDim.x + threadIdx.x;
  if (e < E_EDGES) atomicAdd(&cnt[ei[E_EDGES + e]], 1);
}

__global__ __launch_bounds__(1024) void scan_kernel(const int* __restrict__ cnt,
                                                    int* __restrict__ offs) {
  const int PER = (N_NODES + 1023) / 1024;
  int t = threadIdx.x;
  int start = t * PER;
  int sum = 0;
  for (int i = 0; i < PER; ++i) {
    int idx = start + i;
    if (idx < N_NODES) sum += cnt[idx];
  }
  int lane = t & 63, wid = t >> 6;
  int v = sum;
  for (int off = 1; off < 64; off <<= 1) {
    int u = __shfl_up(v, off, 64);
    if (lane >= off) v += u;
  }
  __shared__ int wsums[16];
  if (lane == 63) wsums[wid] = v;
  __syncthreads();
  if (wid == 0) {
    int w = (lane < 16) ? wsums[lane] : 0;
    for (int off = 1; off < 16; off <<= 1) {
      int u = __shfl_up(w, off, 64);
      if (lane >= off) w += u;
    }
    if (lane < 16) wsums[lane] = w;
  }
  __syncthreads();
  int excl = v - sum + (wid > 0 ? wsums[wid - 1] : 0);
  int run = excl;
  for (int i = 0; i < PER; ++i) {
    int idx = start + i;
    if (idx < N_NODES) { offs[idx] = run; run += cnt[idx]; }
  }
  if (t == 1023) offs[N_NODES] = run;
}

// scatter: CSR-order src*160, dst*160, bf16 edge_attr
__global__ void scatter3(const int* __restrict__ ei, const float* __restrict__ eattr,
                         const int* __restrict__ offs, int* __restrict__ cursor,
                         int* __restrict__ srcm, int* __restrict__ dstm,
                         short* __restrict__ eacsr) {
  int e = blockIdx.x * blockDim.x + threadIdx.x;
  if (e < E_EDGES) {
    int dst = ei[E_EDGES + e];
    int src = ei[e];
    int slot = atomicAdd(&cursor[dst], 1);
    int j = offs[dst] + slot;
    srcm[j] = src * 160;
    dstm[j] = dst * 160;
    const float4* s = (const float4*)&eattr[(size_t)e * ED];
    float4 v0 = s[0], v1 = s[1], v2 = s[2], v3 = s[3];
    short* o = eacsr + (size_t)j * ED;
    short4v w0, w1, w2, w3;
    w0[0]=f2bf(v0.x); w0[1]=f2bf(v0.y); w0[2]=f2bf(v0.z); w0[3]=f2bf(v0.w);
    w1[0]=f2bf(v1.x); w1[1]=f2bf(v1.y); w1[2]=f2bf(v1.z); w1[3]=f2bf(v1.w);
    w2[0]=f2bf(v2.x); w2[1]=f2bf(v2.y); w2[2]=f2bf(v2.z); w2[3]=f2bf(v2.w);
    w3[0]=f2bf(v3.x); w3[1]=f2bf(v3.y); w3[2]=f2bf(v3.z); w3[3]=f2bf(v3.w);
    *(short4v*)(o + 0) = w0; *(short4v*)(o + 4) = w1;
    *(short4v*)(o + 8) = w2; *(short4v*)(o + 12) = w3;
  }
}

// ---------------- fused edge score: ea MFMA + gather + lrelu + att-dot + exp ----------------
// 64 edges per block (E = 64*12500 exactly), 4 waves x 16 edges
__global__ __launch_bounds__(256) void score_mfma(
    const short* __restrict__ eacsr, const int* __restrict__ srcm, const int* __restrict__ dstm,
    const short* __restrict__ WeTp, const short* __restrict__ xl, const short* __restrict__ xr,
    const float* __restrict__ att, float* __restrict__ exj)
{
  int t = threadIdx.x;
  int wave = t >> 6, lane = t & 63;
  int lq = lane >> 4, lc = lane & 15;
  int ebase = blockIdx.x * 64 + wave * 16;
  // A fragment: row (edge-in-tile) = lc, k-segment = lq (k>=16 padded zero)
  bf16x8 af = {};
  if (lq < 2) af = *(const bf16x8*)&eacsr[(size_t)(ebase + lc) * ED + lq * 8];
  f32x4 acc[10] = {};
#pragma unroll
  for (int ct = 0; ct < 10; ++ct) {
    bf16x8 bfv = *(const bf16x8*)&WeTp[(ct * 16 + lc) * 32 + lq * 8];
    acc[ct] = __builtin_amdgcn_mfma_f32_16x16x32_bf16(af, bfv, acc[ct], 0, 0, 0);
  }
  // epilogue: D row = lq*4+rg -> edge ebase+lq*4+rg ; col = ct*16+lc
  int srcv[4], dstv[4];
#pragma unroll
  for (int rg = 0; rg < 4; ++rg) {
    int e = ebase + lq * 4 + rg;
    srcv[rg] = srcm[e];
    dstv[rg] = dstm[e];
  }
  float partial[5][4] = {};
#pragma unroll
  for (int ct = 0; ct < 10; ++ct) {
    int col = ct * 16 + lc;
    float attv = att[col];
#pragma unroll
    for (int rg = 0; rg < 4; ++rg) {
      float z = acc[ct][rg] + bf2f(xl[srcv[rg] + col]) + bf2f(xr[dstv[rg] + col]);
      z = fmaxf(z, NEG_SLOPE * z);
      partial[ct >> 1][rg] = fmaf(z, attv, partial[ct >> 1][rg]);
    }
  }
#pragma unroll
  for (int hh = 0; hh < 5; ++hh) {
#pragma unroll
    for (int rg = 0; rg < 4; ++rg) {
      float p = partial[hh][rg];
      p += __shfl_xor(p, 1, 64);
      p += __shfl_xor(p, 2, 64);
      p += __shfl_xor(p, 4, 64);
      p += __shfl_xor(p, 8, 64);
      if (lc == hh)
        exj[(size_t)hh * E_EDGES + (ebase + lq * 4 + rg)] = __expf(p);
    }
  }
}

// ---------------- aggregation + residual + LN1 ----------------
__global__ __launch_bounds__(160) void attn_agg(
    const int* __restrict__ srcm, const float* __restrict__ exj,
    const short* __restrict__ xl, const float* __restrict__ x,
    const float* __restrict__ b_gat, const float* __restrict__ g1, const float* __restrict__ b1,
    const int* __restrict__ offs,
    float* __restrict__ outb, short* __restrict__ outb_bf)
{
  int i = blockIdx.x;
  int t = threadIdx.x;
  int e0 = offs[i], e1 = offs[i + 1];
  const float* exph = exj + (size_t)(t >> 5) * E_EDGES;
  float agg = 0.f, denom = 0.f;
  for (int j = e0; j < e1; ++j) {
    float ex = exph[j];
    int sb = srcm[j];
    agg = fmaf(ex, bf2f(xl[sb + t]), agg);
    denom += ex;
  }
  float attn = (denom > 0.f) ? agg / denom : 0.f;
  float val = x[(size_t)i * HC + t] + attn + b_gat[t];
  float s1 = val, s2 = val * val;
#pragma unroll
  for (int m = 16; m >= 1; m >>= 1) { s1 += __shfl_xor(s1, m, 32); s2 += __shfl_xor(s2, m, 32); }
  __shared__ float gs1[5], gs2[5];
  __shared__ float smu, srstd;
  if ((t & 31) == 0) { gs1[t >> 5] = s1; gs2[t >> 5] = s2; }
  __syncthreads();
  if (t == 0) {
    float a = 0.f, b = 0.f;
    for (int g = 0; g < 5; ++g) { a += gs1[g]; b += gs2[g]; }
    float mu = a / 160.f, var = b / 160.f - mu * mu;
    smu = mu; srstd = rsqrtf(var + EPS);
  }
  __syncthreads();
  float o = (val - smu) * srstd * g1[t] + b1[t];
  outb[(size_t)i * HC + t] = o;
  outb_bf[(size_t)i * HC + t] = f2bf(o);
}

// ---------------- mlp1 MFMA: h = LN(selu(outb@Wm1+b)) -> bf16 ----------------
__global__ __launch_bounds__(256) void mlp1_mfma(
    const short* __restrict__ ab, const short* __restrict__ W1T,
    const float* __restrict__ b1m, const float* __restrict__ gm, const float* __restrict__ bm,
    short* __restrict__ h)
{
  __shared__ short As[32][40];
  __shared__ float ps1[4][32], ps2[4][32];
  int t = threadIdx.x;
  int wave = t >> 6, lane = t & 63;
  int lq = lane >> 4, lc = lane & 15;
  int row0 = blockIdx.x * 32;
  f32x4 acc[2][8] = {};
  for (int kt = 0; kt < 5; ++kt) {
    int k0 = kt * 32;
    if (t < 128) {
      int r = t >> 2, seg = t & 3;
      int gr = min(row0 + r, N_NODES - 1);
      bf16x8 v = *(const bf16x8*)&ab[(size_t)gr * 160 + k0 + seg * 8];
      *(bf16x8*)&As[r][seg * 8] = v;
    }
    __syncthreads();
    bf16x8 af0 = *(bf16x8*)&As[lc][lq * 8];
    bf16x8 af1 = *(bf16x8*)&As[16 + lc][lq * 8];
#pragma unroll
    for (int ct = 0; ct < 8; ++ct) {
      int cc = wave * 128 + ct * 16 + lc;
      bf16x8 bfv = *(const bf16x8*)&W1T[cc * 160 + k0 + lq * 8];
      acc[0][ct] = __builtin_amdgcn_mfma_f32_16x16x32_bf16(af0, bfv, acc[0][ct], 0, 0, 0);
      acc[1][ct] = __builtin_amdgcn_mfma_f32_16x16x32_bf16(af1, bfv, acc[1][ct], 0, 0, 0);
    }
    __syncthreads();
  }
  float s1[2][4] = {}, s2[2][4] = {};
#pragma unroll
  for (int rt = 0; rt < 2; ++rt)
#pragma unroll
    for (int ct = 0; ct < 8; ++ct)
#pragma unroll
      for (int rg = 0; rg < 4; ++rg) {
        int cc = wave * 128 + ct * 16 + lc;
        float v = selu_f(acc[rt][ct][rg] + b1m[cc]);
        acc[rt][ct][rg] = v;
        s1[rt][rg] += v; s2[rt][rg] += v * v;
      }
#pragma unroll
  for (int m = 1; m <= 8; m <<= 1) {
#pragma unroll
    for (int rt = 0; rt < 2; ++rt)
#pragma unroll
      for (int rg = 0; rg < 4; ++rg) {
        s1[rt][rg] += __shfl_xor(s1[rt][rg], m, 64);
        s2[rt][rg] += __shfl_xor(s2[rt][rg], m, 64);
      }
  }
  if (lc == 0) {
#pragma unroll
    for (int rt = 0; rt < 2; ++rt)
#pragma unroll
      for (int rg = 0; rg < 4; ++rg) {
        ps1[wave][rt * 16 + lq * 4 + rg] = s1[rt][rg];
        ps2[wave][rt * 16 + lq * 4 + rg] = s2[rt][rg];
      }
  }
  __syncthreads();
  float mu[2][4], rstd[2][4];
#pragma unroll
  for (int rt = 0; rt < 2; ++rt)
#pragma unroll
    for (int rg = 0; rg < 4; ++rg) {
      int rl = rt * 16 + lq * 4 + rg;
      float a = ps1[0][rl] + ps1[1][rl] + ps1[2][rl] + ps1[3][rl];
      float b = ps2[0][rl] + ps2[1][rl] + ps2[2][rl] + ps2[3][rl];
      float m_ = a * (1.f / 512.f);
      float var = b * (1.f / 512.f) - m_ * m_;
      mu[rt][rg] = m_; rstd[rt][rg] = rsqrtf(var + EPS);
    }
#pragma unroll
  for (int rt = 0; rt < 2; ++rt)
#pragma unroll
    for (int ct = 0; ct < 8; ++ct)
#pragma unroll
      for (int rg = 0; rg < 4; ++rg) {
        int row = row0 + rt * 16 + lq * 4 + rg;
        int cc = wave * 128 + ct * 16 + lc;
        if (row < N_NODES)
          h[(size_t)row * 512 + cc] =
              f2bf((acc[rt][ct][rg] - mu[rt][rg]) * rstd[rt][rg] * gm[cc] + bm[cc]);
      }
}

// ---------------- mlp2 MFMA: y = LN(outb + h@Wm2 + b) ----------------
__global__ __launch_bounds__(256) void mlp2_mfma(
    const short* __restrict__ hb, const short* __restrict__ W2T,
    const float* __restrict__ b2m, const float* __restrict__ outb,
    const float* __restrict__ g2, const float* __restrict__ b2,
    float* __restrict__ y)
{
  __shared__ short As[64][40];
  int t = threadIdx.x;
  int wave = t >> 6, lane = t & 63;
  int lq = lane >> 4, lc = lane & 15;
  int row0 = blockIdx.x * 64;
  f32x4 acc[10] = {};
  for (int kt = 0; kt < 16; ++kt) {
    int k0 = kt * 32;
    {
      int r = t >> 2, seg = t & 3;
      int gr = min(row0 + r, N_NODES - 1);
      bf16x8 v = *(const bf16x8*)&hb[(size_t)gr * 512 + k0 + seg * 8];
      *(bf16x8*)&As[r][seg * 8] = v;
    }
    __syncthreads();
    bf16x8 af = *(bf16x8*)&As[wave * 16 + lc][lq * 8];
#pragma unroll
    for (int ct = 0; ct < 10; ++ct) {
      int cc = ct * 16 + lc;
      bf16x8 bfv = *(const bf16x8*)&W2T[cc * 512 + k0 + lq * 8];
      acc[ct] = __builtin_amdgcn_mfma_f32_16x16x32_bf16(af, bfv, acc[ct], 0, 0, 0);
    }
    __syncthreads();
  }
  float s1[4] = {}, s2[4] = {};
#pragma unroll
  for (int ct = 0; ct < 10; ++ct) {
    int col = ct * 16 + lc;
#pragma unroll
    for (int rg = 0; rg < 4; ++rg) {
      int rowl = min(row0 + wave * 16 + lq * 4 + rg, N_NODES - 1);
      float v = acc[ct][rg] + b2m[col] + outb[(size_t)rowl * 160 + col];
      acc[ct][rg] = v;
      s1[rg] += v; s2[rg] += v * v;
    }
  }
#pragma unroll
  for (int m = 1; m <= 8; m <<= 1) {
#pragma unroll
    for (int rg = 0; rg < 4; ++rg) {
      s1[rg] += __shfl_xor(s1[rg], m, 64);
      s2[rg] += __shfl_xor(s2[rg], m, 64);
    }
  }
  float mu[4], rstd[4];
#pragma unroll
  for (int rg = 0; rg < 4; ++rg) {
    float m_ = s1[rg] * (1.f / 160.f);
    float var = s2[rg] * (1.f / 160.f) - m_ * m_;
    mu[rg] = m_; rstd[rg] = rsqrtf(var + EPS);
  }
#pragma unroll
  for (int ct = 0; ct < 10; ++ct) {
    int col = ct * 16 + lc;
#pragma unroll
    for (int rg = 0; rg < 4; ++rg) {
      int row = row0 + wave * 16 + lq * 4 + rg;
      if (row < N_NODES)
        y[(size_t)row * 160 + col] = (acc[ct][rg] - mu[rg]) * rstd[rg] * g2[col] + b2[col];
    }
  }
}

extern "C" void kernel_launch(void* const* d_in, const int* in_sizes, int n_in,
                              void* d_out, int out_size, void* d_ws, size_t ws_size,
                              hipStream_t stream) {
  const float* x     = (const float*)d_in[0];
  const int*   ei    = (const int*)d_in[1];
  const float* eattr = (const float*)d_in[2];
  const float* Wl    = (const float*)d_in[5];
  const float* bl    = (const float*)d_in[6];
  const float* Wr    = (const float*)d_in[7];
  const float* br    = (const float*)d_in[8];
  const float* We    = (const float*)d_in[9];
  const float* att   = (const float*)d_in[10];
  const float* bgat  = (const float*)d_in[11];
  const float* g1    = (const float*)d_in[12];
  const float* b1    = (const float*)d_in[13];
  const float* Wm1   = (const float*)d_in[14];
  const float* bm1   = (const float*)d_in[15];
  const float* gm    = (const float*)d_in[16];
  const float* bm    = (const float*)d_in[17];
  const float* Wm2   = (const float*)d_in[18];
  const float* bm2   = (const float*)d_in[19];
  const float* g2    = (const float*)d_in[20];
  const float* b2    = (const float*)d_in[21];
  float* y = (float*)d_out;

  char* p = (char*)d_ws;
  auto alloc = [&](size_t bytes) {
    void* q = p;
    p += (bytes + 255) & ~(size_t)255;
    return q;
  };
  short* xb      = (short*)alloc((size_t)N_NODES * 160 * 2);
  short* xlb     = (short*)alloc((size_t)N_NODES * 160 * 2);
  short* xrb     = (short*)alloc((size_t)N_NODES * 160 * 2);
  float* outb    = (float*)alloc((size_t)N_NODES * 160 * 4);
  short* outb_bf = (short*)alloc((size_t)N_NODES * 160 * 2);
  short* hb      = (short*)alloc((size_t)N_NODES * 512 * 2);
  short* eacsr   = (short*)alloc((size_t)E_EDGES * ED * 2);
  int*   srcm    = (int*)alloc((size_t)E_EDGES * 4);
  int*   dstm    = (int*)alloc((size_t)E_EDGES * 4);
  float* exj     = (float*)alloc((size_t)H * E_EDGES * 4);
  short* WlT     = (short*)alloc(160 * 160 * 2);
  short* WrT     = (short*)alloc(160 * 160 * 2);
  short* W1T     = (short*)alloc(512 * 160 * 2);
  short* W2T     = (short*)alloc(160 * 512 * 2);
  short* WeTp    = (short*)alloc(160 * 32 * 2);
  int*   cnt     = (int*)alloc((size_t)N_NODES * 4);
  int*   offs    = (int*)alloc((size_t)(N_NODES + 1) * 4);
  int*   cursor  = (int*)alloc((size_t)N_NODES * 4);

  hipMemsetAsync(cnt, 0, (size_t)N_NODES * 4, stream);
  hipMemsetAsync(cursor, 0, (size_t)N_NODES * 4, stream);

  prep_weights<<<(220160 + 255) / 256, 256, 0, stream>>>(Wl, Wr, Wm1, Wm2, We,
                                                         WlT, WrT, W1T, W2T, WeTp);
  convert_x<<<(N_NODES * 160 / 8 + 255) / 256, 256, 0, stream>>>(x, xb);
  count_kernel<<<(E_EDGES + 255) / 256, 256, 0, stream>>>(ei, cnt);
  scan_kernel<<<1, 1024, 0, stream>>>(cnt, offs);
  scatter3<<<(E_EDGES + 255) / 256, 256, 0, stream>>>(ei, eattr, offs, cursor,
                                                      srcm, dstm, eacsr);
  proj_mfma<<<(N_NODES + 63) / 64, 256, 0, stream>>>(xb, WlT, WrT, bl, br, xlb, xrb);
  score_mfma<<<E_EDGES / 64, 256, 0, stream>>>(eacsr, srcm, dstm, WeTp, xlb, xrb, att, exj);
  attn_agg<<<N_NODES, 160, 0, stream>>>(srcm, exj, xlb, x, bgat, g1, b1, offs, outb, outb_bf);
  mlp1_mfma<<<(N_NODES + 31) / 32, 256, 0, stream>>>(outb_bf, W1T, bm1, gm, bm, hb);
  mlp2_mfma<<<(N_NODES + 63) / 64, 256, 0, stream>>>(hb, W2T, bm2, outb, g2, b2, y);
}

// Round 4
// 783.301 us; speedup vs baseline: 1.0364x; 1.0364x over previous
//
#include <hip/hip_runtime.h>
#include <math.h>

#define N_NODES 50000
#define D 160
#define H 5
#define C 32
#define HC 160
#define E_EDGES 800000
#define ED 16
#define HID 512
#define EPS 1e-5f
#define NEG_SLOPE 0.2f

typedef __attribute__((ext_vector_type(8))) short bf16x8;
typedef __attribute__((ext_vector_type(4))) float f32x4;
typedef __attribute__((ext_vector_type(4))) short short4v;

__device__ inline float bf2f(short s) {
  unsigned u = ((unsigned)(unsigned short)s) << 16;
  return __builtin_bit_cast(float, u);
}
__device__ inline short f2bf(float f) {
  unsigned u = __builtin_bit_cast(unsigned, f);
  u = u + 0x7fffu + ((u >> 16) & 1u);
  return (short)(u >> 16);
}
__device__ inline float selu_f(float v) {
  return 1.0507009873554805f * (v > 0.f ? v : 1.6732632423543772f * (__expf(v) - 1.f));
}

// ---------------- weight prep: transpose + bf16 (+ padded WeT) ----------------
__global__ void prep_weights(const float* __restrict__ Wl, const float* __restrict__ Wr,
                             const float* __restrict__ Wm1, const float* __restrict__ Wm2,
                             const float* __restrict__ We,
                             short* __restrict__ WlT, short* __restrict__ WrT,
                             short* __restrict__ W1T, short* __restrict__ W2T,
                             short* __restrict__ WeTp) {
  int i = blockIdx.x * blockDim.x + threadIdx.x;
  if (i < 25600) { int n = i / 160, k = i % 160; WlT[n*160 + k] = f2bf(Wl[k*160 + n]); return; }
  i -= 25600;
  if (i < 25600) { int n = i / 160, k = i % 160; WrT[n*160 + k] = f2bf(Wr[k*160 + n]); return; }
  i -= 25600;
  if (i < 81920) { int n = i / 160, k = i % 160; W1T[n*160 + k] = f2bf(Wm1[k*512 + n]); return; }
  i -= 81920;
  if (i < 81920) { int n = i / 512, k = i % 512; W2T[n*512 + k] = f2bf(Wm2[k*160 + n]); return; }
  i -= 81920;
  if (i < 5120) { int col = i / 32, k = i % 32;
    WeTp[col*32 + k] = (k < ED) ? f2bf(We[k*160 + col]) : (short)0; }
}

// ---------------- convert x to bf16 ----------------
__global__ void convert_x(const float* __restrict__ x, short* __restrict__ xb) {
  int i = blockIdx.x * blockDim.x + threadIdx.x;
  if (i < N_NODES * D / 8) {
    const float4* s = (const float4*)(x + (size_t)i * 8);
    float4 a = s[0], b = s[1];
    bf16x8 o;
    o[0] = f2bf(a.x); o[1] = f2bf(a.y); o[2] = f2bf(a.z); o[3] = f2bf(a.w);
    o[4] = f2bf(b.x); o[5] = f2bf(b.y); o[6] = f2bf(b.z); o[7] = f2bf(b.w);
    *(bf16x8*)(xb + (size_t)i * 8) = o;
  }
}

// ---------------- proj MFMA: xl = x@Wl+bl, xr = x@Wr+br (bf16 out) ----------------
__global__ __launch_bounds__(256) void proj_mfma(
    const short* __restrict__ xb, const short* __restrict__ WlT, const short* __restrict__ WrT,
    const float* __restrict__ bl, const float* __restrict__ br,
    short* __restrict__ xl, short* __restrict__ xr)
{
  __shared__ short As[64][40];
  int t = threadIdx.x;
  int wave = t >> 6, lane = t & 63;
  int lq = lane >> 4, lc = lane & 15;
  int row0 = blockIdx.x * 64;
  f32x4 accl[10] = {}, accr[10] = {};
  for (int kt = 0; kt < 5; ++kt) {
    int k0 = kt * 32;
    {
      int r = t >> 2, seg = t & 3;
      int gr = min(row0 + r, N_NODES - 1);
      bf16x8 v = *(const bf16x8*)&xb[(size_t)gr * 160 + k0 + seg * 8];
      *(bf16x8*)&As[r][seg * 8] = v;
    }
    __syncthreads();
    bf16x8 af = *(bf16x8*)&As[wave * 16 + lc][lq * 8];
#pragma unroll
    for (int ct = 0; ct < 10; ++ct) {
      int cc = ct * 16 + lc;
      bf16x8 bfl = *(const bf16x8*)&WlT[cc * 160 + k0 + lq * 8];
      accl[ct] = __builtin_amdgcn_mfma_f32_16x16x32_bf16(af, bfl, accl[ct], 0, 0, 0);
      bf16x8 bfr = *(const bf16x8*)&WrT[cc * 160 + k0 + lq * 8];
      accr[ct] = __builtin_amdgcn_mfma_f32_16x16x32_bf16(af, bfr, accr[ct], 0, 0, 0);
    }
    __syncthreads();
  }
#pragma unroll
  for (int ct = 0; ct < 10; ++ct) {
    int col = ct * 16 + lc;
    float bbl = bl[col], bbr = br[col];
#pragma unroll
    for (int rg = 0; rg < 4; ++rg) {
      int row = row0 + wave * 16 + lq * 4 + rg;
      if (row < N_NODES) {
        xl[(size_t)row * 160 + col] = f2bf(accl[ct][rg] + bbl);
        xr[(size_t)row * 160 + col] = f2bf(accr[ct][rg] + bbr);
      }
    }
  }
}

// ---------------- CSR build ----------------
__global__ void count_kernel(const int* __restrict__ ei, int* __restrict__ cnt) {
  int e = blockIdx.x * blockDim.x + threadIdx.x;
  if (e < E_EDGES) atomicAdd(&cnt[ei[E_EDGES + e]], 1);
}

__global__ __launch_bounds__(1024) void scan_kernel(const int* __restrict__ cnt,
                                                    int* __restrict__ offs) {
  const int PER = (N_NODES + 1023) / 1024;
  int t = threadIdx.x;
  int start = t * PER;
  int sum = 0;
  for (int i = 0; i < PER; ++i) {
    int idx = start + i;
    if (idx < N_NODES) sum += cnt[idx];
  }
  int lane = t & 63, wid = t >> 6;
  int v = sum;
  for (int off = 1; off < 64; off <<= 1) {
    int u = __shfl_up(v, off, 64);
    if (lane >= off) v += u;
  }
  __shared__ int wsums[16];
  if (lane == 63) wsums[wid] = v;
  __syncthreads();
  if (wid == 0) {
    int w = (lane < 16) ? wsums[lane] : 0;
    for (int off = 1; off < 16; off <<= 1) {
      int u = __shfl_up(w, off, 64);
      if (lane >= off) w += u;
    }
    if (lane < 16) wsums[lane] = w;
  }
  __syncthreads();
  int excl = v - sum + (wid > 0 ? wsums[wid - 1] : 0);
  int run = excl;
  for (int i = 0; i < PER; ++i) {
    int idx = start + i;
    if (idx < N_NODES) { offs[idx] = run; run += cnt[idx]; }
  }
  if (t == 1023) offs[N_NODES] = run;
}

// scatter: CSR-order src*160, bf16 edge_attr
__global__ void scatter3(const int* __restrict__ ei, const float* __restrict__ eattr,
                         const int* __restrict__ offs, int* __restrict__ cursor,
                         int* __restrict__ srcm, short* __restrict__ eacsr) {
  int e = blockIdx.x * blockDim.x + threadIdx.x;
  if (e < E_EDGES) {
    int dst = ei[E_EDGES + e];
    int src = ei[e];
    int slot = atomicAdd(&cursor[dst], 1);
    int j = offs[dst] + slot;
    srcm[j] = src * 160;
    const float4* s = (const float4*)&eattr[(size_t)e * ED];
    float4 v0 = s[0], v1 = s[1], v2 = s[2], v3 = s[3];
    short* o = eacsr + (size_t)j * ED;
    short4v w0, w1, w2, w3;
    w0[0]=f2bf(v0.x); w0[1]=f2bf(v0.y); w0[2]=f2bf(v0.z); w0[3]=f2bf(v0.w);
    w1[0]=f2bf(v1.x); w1[1]=f2bf(v1.y); w1[2]=f2bf(v1.z); w1[3]=f2bf(v1.w);
    w2[0]=f2bf(v2.x); w2[1]=f2bf(v2.y); w2[2]=f2bf(v2.z); w2[3]=f2bf(v2.w);
    w3[0]=f2bf(v3.x); w3[1]=f2bf(v3.y); w3[2]=f2bf(v3.z); w3[3]=f2bf(v3.w);
    *(short4v*)(o + 0) = w0; *(short4v*)(o + 4) = w1;
    *(short4v*)(o + 8) = w2; *(short4v*)(o + 12) = w3;
  }
}

// ---------------- fused attention: one wave per dst node ----------------
// score (ea MFMA + gathers + lrelu + att-dot + exp) AND aggregation AND
// residual+LN1, all in registers. 4 independent waves per block, no LDS.
__global__ __launch_bounds__(256) void attn_fused(
    const short* __restrict__ eacsr, const int* __restrict__ srcm,
    const short* __restrict__ WeTp, const short* __restrict__ xl, const short* __restrict__ xr,
    const float* __restrict__ att, const float* __restrict__ x,
    const float* __restrict__ b_gat, const float* __restrict__ g1, const float* __restrict__ b1,
    const int* __restrict__ offs,
    float* __restrict__ outb, short* __restrict__ outb_bf)
{
  int t = threadIdx.x;
  int wave = t >> 6, lane = t & 63;
  int lq = lane >> 4, lc = lane & 15;
  int i = blockIdx.x * 4 + wave;    // dst node (grid*4 == N exactly)
  int e0 = offs[i], e1 = offs[i + 1];

  float xrv[10], attv[10];
#pragma unroll
  for (int ct = 0; ct < 10; ++ct) {
    xrv[ct] = bf2f(xr[(size_t)i * 160 + ct * 16 + lc]);
    attv[ct] = att[ct * 16 + lc];
  }
  float aggc[10] = {};
  float den[5] = {};
  const f32x4 zero4 = {};

  for (int j0 = e0; j0 < e1; j0 += 16) {
    // A fragment: row = lc (edge j0+lc), k-seg = lq (k>=16 zero-padded)
    bf16x8 af = {};
    if (lq < 2) {
      int jr = min(j0 + lc, e1 - 1);
      af = *(const bf16x8*)&eacsr[(size_t)jr * ED + lq * 8];
    }
    f32x4 acc[10];
#pragma unroll
    for (int ct = 0; ct < 10; ++ct) {
      bf16x8 bfv = *(const bf16x8*)&WeTp[(ct * 16 + lc) * 32 + lq * 8];
      acc[ct] = __builtin_amdgcn_mfma_f32_16x16x32_bf16(af, bfv, zero4, 0, 0, 0);
    }
    int src[4]; bool ok[4];
#pragma unroll
    for (int rg = 0; rg < 4; ++rg) {
      int j = j0 + lq * 4 + rg;
      ok[rg] = (j < e1);
      src[rg] = srcm[min(j, e1 - 1)];
    }
    float xlv[10][4];
    float partial[5][4] = {};
#pragma unroll
    for (int ct = 0; ct < 10; ++ct) {
#pragma unroll
      for (int rg = 0; rg < 4; ++rg) {
        float v = bf2f(xl[src[rg] + ct * 16 + lc]);
        xlv[ct][rg] = v;
        float z = acc[ct][rg] + v + xrv[ct];
        z = fmaxf(z, NEG_SLOPE * z);
        partial[ct >> 1][rg] = fmaf(z, attv[ct], partial[ct >> 1][rg]);
      }
    }
    // reduce over the 16 lc lanes -> per-(head, edge) score; exp; mask tail
#pragma unroll
    for (int hh = 0; hh < 5; ++hh) {
#pragma unroll
      for (int rg = 0; rg < 4; ++rg) {
        float p = partial[hh][rg];
        p += __shfl_xor(p, 1, 64);
        p += __shfl_xor(p, 2, 64);
        p += __shfl_xor(p, 4, 64);
        p += __shfl_xor(p, 8, 64);
        float ex = ok[rg] ? __expf(p) : 0.f;   // softmax shift-invariant; scores O(1)
        den[hh] += ex;
        partial[hh][rg] = ex;                   // reuse as ex
      }
    }
#pragma unroll
    for (int ct = 0; ct < 10; ++ct)
#pragma unroll
      for (int rg = 0; rg < 4; ++rg)
        aggc[ct] = fmaf(partial[ct >> 1][rg], xlv[ct][rg], aggc[ct]);
  }
  // combine the 4 lq edge-groups
#pragma unroll
  for (int ct = 0; ct < 10; ++ct) {
    aggc[ct] += __shfl_xor(aggc[ct], 16, 64);
    aggc[ct] += __shfl_xor(aggc[ct], 32, 64);
  }
#pragma unroll
  for (int hh = 0; hh < 5; ++hh) {
    den[hh] += __shfl_xor(den[hh], 16, 64);
    den[hh] += __shfl_xor(den[hh], 32, 64);
  }
  // residual + LN over 160 cols (each lane holds cols {ct*16+lc}, replicated over lq)
  float val[10];
  float s1 = 0.f, s2 = 0.f;
#pragma unroll
  for (int ct = 0; ct < 10; ++ct) {
    float d = den[ct >> 1];
    float attn = (d > 0.f) ? aggc[ct] / d : 0.f;
    float v = x[(size_t)i * 160 + ct * 16 + lc] + attn + b_gat[ct * 16 + lc];
    val[ct] = v;
    s1 += v; s2 += v * v;
  }
#pragma unroll
  for (int m = 1; m <= 8; m <<= 1) { s1 += __shfl_xor(s1, m, 64); s2 += __shfl_xor(s2, m, 64); }
  float mu = s1 * (1.f / 160.f);
  float var = s2 * (1.f / 160.f) - mu * mu;
  float rstd = rsqrtf(var + EPS);
  if (lq == 0) {
#pragma unroll
    for (int ct = 0; ct < 10; ++ct) {
      int col = ct * 16 + lc;
      float o = (val[ct] - mu) * rstd * g1[col] + b1[col];
      outb[(size_t)i * 160 + col] = o;
      outb_bf[(size_t)i * 160 + col] = f2bf(o);
    }
  }
}

// ---------------- mlp1 MFMA: h = LN(selu(outb@Wm1+b)) -> bf16 ----------------
__global__ __launch_bounds__(256) void mlp1_mfma(
    const short* __restrict__ ab, const short* __restrict__ W1T,
    const float* __restrict__ b1m, const float* __restrict__ gm, const float* __restrict__ bm,
    short* __restrict__ h)
{
  __shared__ short As[32][40];
  __shared__ float ps1[4][32], ps2[4][32];
  int t = threadIdx.x;
  int wave = t >> 6, lane = t & 63;
  int lq = lane >> 4, lc = lane & 15;
  int row0 = blockIdx.x * 32;
  f32x4 acc[2][8] = {};
  for (int kt = 0; kt < 5; ++kt) {
    int k0 = kt * 32;
    if (t < 128) {
      int r = t >> 2, seg = t & 3;
      int gr = min(row0 + r, N_NODES - 1);
      bf16x8 v = *(const bf16x8*)&ab[(size_t)gr * 160 + k0 + seg * 8];
      *(bf16x8*)&As[r][seg * 8] = v;
    }
    __syncthreads();
    bf16x8 af0 = *(bf16x8*)&As[lc][lq * 8];
    bf16x8 af1 = *(bf16x8*)&As[16 + lc][lq * 8];
#pragma unroll
    for (int ct = 0; ct < 8; ++ct) {
      int cc = wave * 128 + ct * 16 + lc;
      bf16x8 bfv = *(const bf16x8*)&W1T[cc * 160 + k0 + lq * 8];
      acc[0][ct] = __builtin_amdgcn_mfma_f32_16x16x32_bf16(af0, bfv, acc[0][ct], 0, 0, 0);
      acc[1][ct] = __builtin_amdgcn_mfma_f32_16x16x32_bf16(af1, bfv, acc[1][ct], 0, 0, 0);
    }
    __syncthreads();
  }
  float s1[2][4] = {}, s2[2][4] = {};
#pragma unroll
  for (int rt = 0; rt < 2; ++rt)
#pragma unroll
    for (int ct = 0; ct < 8; ++ct)
#pragma unroll
      for (int rg = 0; rg < 4; ++rg) {
        int cc = wave * 128 + ct * 16 + lc;
        float v = selu_f(acc[rt][ct][rg] + b1m[cc]);
        acc[rt][ct][rg] = v;
        s1[rt][rg] += v; s2[rt][rg] += v * v;
      }
#pragma unroll
  for (int m = 1; m <= 8; m <<= 1) {
#pragma unroll
    for (int rt = 0; rt < 2; ++rt)
#pragma unroll
      for (int rg = 0; rg < 4; ++rg) {
        s1[rt][rg] += __shfl_xor(s1[rt][rg], m, 64);
        s2[rt][rg] += __shfl_xor(s2[rt][rg], m, 64);
      }
  }
  if (lc == 0) {
#pragma unroll
    for (int rt = 0; rt < 2; ++rt)
#pragma unroll
      for (int rg = 0; rg < 4; ++rg) {
        ps1[wave][rt * 16 + lq * 4 + rg] = s1[rt][rg];
        ps2[wave][rt * 16 + lq * 4 + rg] = s2[rt][rg];
      }
  }
  __syncthreads();
  float mu[2][4], rstd[2][4];
#pragma unroll
  for (int rt = 0; rt < 2; ++rt)
#pragma unroll
    for (int rg = 0; rg < 4; ++rg) {
      int rl = rt * 16 + lq * 4 + rg;
      float a = ps1[0][rl] + ps1[1][rl] + ps1[2][rl] + ps1[3][rl];
      float b = ps2[0][rl] + ps2[1][rl] + ps2[2][rl] + ps2[3][rl];
      float m_ = a * (1.f / 512.f);
      float var = b * (1.f / 512.f) - m_ * m_;
      mu[rt][rg] = m_; rstd[rt][rg] = rsqrtf(var + EPS);
    }
#pragma unroll
  for (int rt = 0; rt < 2; ++rt)
#pragma unroll
    for (int ct = 0; ct < 8; ++ct)
#pragma unroll
      for (int rg = 0; rg < 4; ++rg) {
        int row = row0 + rt * 16 + lq * 4 + rg;
        int cc = wave * 128 + ct * 16 + lc;
        if (row < N_NODES)
          h[(size_t)row * 512 + cc] =
              f2bf((acc[rt][ct][rg] - mu[rt][rg]) * rstd[rt][rg] * gm[cc] + bm[cc]);
      }
}

// ---------------- mlp2 MFMA: y = LN(outb + h@Wm2 + b) ----------------
// 128-row tile, K unrolled by 2 (8 staged iterations of K=64)
__global__ __launch_bounds__(256) void mlp2_mfma(
    const short* __restrict__ hb, const short* __restrict__ W2T,
    const float* __restrict__ b2m, const float* __restrict__ outb,
    const float* __restrict__ g2, const float* __restrict__ b2,
    float* __restrict__ y)
{
  __shared__ short As[128][72];   // 64 k + 8 pad shorts; 18.4 KB
  int t = threadIdx.x;
  int wave = t >> 6, lane = t & 63;
  int lq = lane >> 4, lc = lane & 15;
  int row0 = blockIdx.x * 128;
  f32x4 acc[2][10] = {};
  for (int kt = 0; kt < 8; ++kt) {
    int k0 = kt * 64;
    __syncthreads();
#pragma unroll
    for (int q = 0; q < 4; ++q) {
      int idx = t + 256 * q;
      int r = idx >> 3, seg = idx & 7;
      int gr = min(row0 + r, N_NODES - 1);
      *(bf16x8*)&As[r][seg * 8] = *(const bf16x8*)&hb[(size_t)gr * 512 + k0 + seg * 8];
    }
    __syncthreads();
#pragma unroll
    for (int ks = 0; ks < 2; ++ks) {
      bf16x8 af0 = *(bf16x8*)&As[wave * 32 + lc][ks * 32 + lq * 8];
      bf16x8 af1 = *(bf16x8*)&As[wave * 32 + 16 + lc][ks * 32 + lq * 8];
#pragma unroll
      for (int ct = 0; ct < 10; ++ct) {
        bf16x8 bfv = *(const bf16x8*)&W2T[(ct * 16 + lc) * 512 + k0 + ks * 32 + lq * 8];
        acc[0][ct] = __builtin_amdgcn_mfma_f32_16x16x32_bf16(af0, bfv, acc[0][ct], 0, 0, 0);
        acc[1][ct] = __builtin_amdgcn_mfma_f32_16x16x32_bf16(af1, bfv, acc[1][ct], 0, 0, 0);
      }
    }
  }
  float s1[2][4] = {}, s2[2][4] = {};
#pragma unroll
  for (int rt = 0; rt < 2; ++rt)
#pragma unroll
    for (int ct = 0; ct < 10; ++ct) {
      int col = ct * 16 + lc;
#pragma unroll
      for (int rg = 0; rg < 4; ++rg) {
        int rowl = min(row0 + wave * 32 + rt * 16 + lq * 4 + rg, N_NODES - 1);
        float v = acc[rt][ct][rg] + b2m[col] + outb[(size_t)rowl * 160 + col];
        acc[rt][ct][rg] = v;
        s1[rt][rg] += v; s2[rt][rg] += v * v;
      }
    }
#pragma unroll
  for (int m = 1; m <= 8; m <<= 1) {
#pragma unroll
    for (int rt = 0; rt < 2; ++rt)
#pragma unroll
      for (int rg = 0; rg < 4; ++rg) {
        s1[rt][rg] += __shfl_xor(s1[rt][rg], m, 64);
        s2[rt][rg] += __shfl_xor(s2[rt][rg], m, 64);
      }
  }
  float mu[2][4], rstd[2][4];
#pragma unroll
  for (int rt = 0; rt < 2; ++rt)
#pragma unroll
    for (int rg = 0; rg < 4; ++rg) {
      float m_ = s1[rt][rg] * (1.f / 160.f);
      float var = s2[rt][rg] * (1.f / 160.f) - m_ * m_;
      mu[rt][rg] = m_; rstd[rt][rg] = rsqrtf(var + EPS);
    }
#pragma unroll
  for (int rt = 0; rt < 2; ++rt)
#pragma unroll
    for (int ct = 0; ct < 10; ++ct) {
      int col = ct * 16 + lc;
#pragma unroll
      for (int rg = 0; rg < 4; ++rg) {
        int row = row0 + wave * 32 + rt * 16 + lq * 4 + rg;
        if (row < N_NODES)
          y[(size_t)row * 160 + col] = (acc[rt][ct][rg] - mu[rt][rg]) * rstd[rt][rg] * g2[col] + b2[col];
      }
    }
}

extern "C" void kernel_launch(void* const* d_in, const int* in_sizes, int n_in,
                              void* d_out, int out_size, void* d_ws, size_t ws_size,
                              hipStream_t stream) {
  const float* x     = (const float*)d_in[0];
  const int*   ei    = (const int*)d_in[1];
  const float* eattr = (const float*)d_in[2];
  const float* Wl    = (const float*)d_in[5];
  const float* bl    = (const float*)d_in[6];
  const float* Wr    = (const float*)d_in[7];
  const float* br    = (const float*)d_in[8];
  const float* We    = (const float*)d_in[9];
  const float* att   = (const float*)d_in[10];
  const float* bgat  = (const float*)d_in[11];
  const float* g1    = (const float*)d_in[12];
  const float* b1    = (const float*)d_in[13];
  const float* Wm1   = (const float*)d_in[14];
  const float* bm1   = (const float*)d_in[15];
  const float* gm    = (const float*)d_in[16];
  const float* bm    = (const float*)d_in[17];
  const float* Wm2   = (const float*)d_in[18];
  const float* bm2   = (const float*)d_in[19];
  const float* g2    = (const float*)d_in[20];
  const float* b2    = (const float*)d_in[21];
  float* y = (float*)d_out;

  char* p = (char*)d_ws;
  auto alloc = [&](size_t bytes) {
    void* q = p;
    p += (bytes + 255) & ~(size_t)255;
    return q;
  };
  short* xb      = (short*)alloc((size_t)N_NODES * 160 * 2);
  short* xlb     = (short*)alloc((size_t)N_NODES * 160 * 2);
  short* xrb     = (short*)alloc((size_t)N_NODES * 160 * 2);
  float* outb    = (float*)alloc((size_t)N_NODES * 160 * 4);
  short* outb_bf = (short*)alloc((size_t)N_NODES * 160 * 2);
  short* hb      = (short*)alloc((size_t)N_NODES * 512 * 2);
  short* eacsr   = (short*)alloc((size_t)E_EDGES * ED * 2);
  int*   srcm    = (int*)alloc((size_t)E_EDGES * 4);
  short* WlT     = (short*)alloc(160 * 160 * 2);
  short* WrT     = (short*)alloc(160 * 160 * 2);
  short* W1T     = (short*)alloc(512 * 160 * 2);
  short* W2T     = (short*)alloc(160 * 512 * 2);
  short* WeTp    = (short*)alloc(160 * 32 * 2);
  int*   cnt     = (int*)alloc((size_t)N_NODES * 4);
  int*   offs    = (int*)alloc((size_t)(N_NODES + 1) * 4);
  int*   cursor  = (int*)alloc((size_t)N_NODES * 4);

  hipMemsetAsync(cnt, 0, (size_t)N_NODES * 4, stream);
  hipMemsetAsync(cursor, 0, (size_t)N_NODES * 4, stream);

  prep_weights<<<(220160 + 255) / 256, 256, 0, stream>>>(Wl, Wr, Wm1, Wm2, We,
                                                         WlT, WrT, W1T, W2T, WeTp);
  convert_x<<<(N_NODES * 160 / 8 + 255) / 256, 256, 0, stream>>>(x, xb);
  count_kernel<<<(E_EDGES + 255) / 256, 256, 0, stream>>>(ei, cnt);
  scan_kernel<<<1, 1024, 0, stream>>>(cnt, offs);
  scatter3<<<(E_EDGES + 255) / 256, 256, 0, stream>>>(ei, eattr, offs, cursor, srcm, eacsr);
  proj_mfma<<<(N_NODES + 63) / 64, 256, 0, stream>>>(xb, WlT, WrT, bl, br, xlb, xrb);
  attn_fused<<<N_NODES / 4, 256, 0, stream>>>(eacsr, srcm, WeTp, xlb, xrb, att, x,
                                              bgat, g1, b1, offs, outb, outb_bf);
  mlp1_mfma<<<(N_NODES + 31) / 32, 256, 0, stream>>>(outb_bf, W1T, bm1, gm, bm, hb);
  mlp2_mfma<<<(N_NODES + 127) / 128, 256, 0, stream>>>(hb, W2T, bm2, outb, g2, b2, y);
}

// Round 5
// 677.186 us; speedup vs baseline: 1.1988x; 1.1567x over previous
//
#include <hip/hip_runtime.h>
#include <math.h>

#define N_NODES 50000
#define D 160
#define H 5
#define C 32
#define HC 160
#define E_EDGES 800000
#define ED 16
#define HID 512
#define EPS 1e-5f
#define NEG_SLOPE 0.2f

typedef __attribute__((ext_vector_type(8))) short bf16x8;
typedef __attribute__((ext_vector_type(4))) float f32x4;
typedef __attribute__((ext_vector_type(4))) short short4v;

__device__ inline float bf2f(short s) {
  unsigned u = ((unsigned)(unsigned short)s) << 16;
  return __builtin_bit_cast(float, u);
}
__device__ inline short f2bf(float f) {
  unsigned u = __builtin_bit_cast(unsigned, f);
  u = u + 0x7fffu + ((u >> 16) & 1u);
  return (short)(u >> 16);
}
__device__ inline float selu_f(float v) {
  return 1.0507009873554805f * (v > 0.f ? v : 1.6732632423543772f * (__expf(v) - 1.f));
}

// ---------------- weight prep: transpose + bf16 (+ padded WeT) ----------------
__global__ void prep_weights(const float* __restrict__ Wl, const float* __restrict__ Wr,
                             const float* __restrict__ Wm1, const float* __restrict__ Wm2,
                             const float* __restrict__ We,
                             short* __restrict__ WlT, short* __restrict__ WrT,
                             short* __restrict__ W1T, short* __restrict__ W2T,
                             short* __restrict__ WeTp) {
  int i = blockIdx.x * blockDim.x + threadIdx.x;
  if (i < 25600) { int n = i / 160, k = i % 160; WlT[n*160 + k] = f2bf(Wl[k*160 + n]); return; }
  i -= 25600;
  if (i < 25600) { int n = i / 160, k = i % 160; WrT[n*160 + k] = f2bf(Wr[k*160 + n]); return; }
  i -= 25600;
  if (i < 81920) { int n = i / 160, k = i % 160; W1T[n*160 + k] = f2bf(Wm1[k*512 + n]); return; }
  i -= 81920;
  if (i < 81920) { int n = i / 512, k = i % 512; W2T[n*512 + k] = f2bf(Wm2[k*160 + n]); return; }
  i -= 81920;
  if (i < 5120) { int col = i / 32, k = i % 32;
    WeTp[col*32 + k] = (k < ED) ? f2bf(We[k*160 + col]) : (short)0; }
}

// ---------------- convert x to bf16 ----------------
__global__ void convert_x(const float* __restrict__ x, short* __restrict__ xb) {
  int i = blockIdx.x * blockDim.x + threadIdx.x;
  if (i < N_NODES * D / 8) {
    const float4* s = (const float4*)(x + (size_t)i * 8);
    float4 a = s[0], b = s[1];
    bf16x8 o;
    o[0] = f2bf(a.x); o[1] = f2bf(a.y); o[2] = f2bf(a.z); o[3] = f2bf(a.w);
    o[4] = f2bf(b.x); o[5] = f2bf(b.y); o[6] = f2bf(b.z); o[7] = f2bf(b.w);
    *(bf16x8*)(xb + (size_t)i * 8) = o;
  }
}

// ---------------- proj MFMA: xl = x@Wl+bl, xr = x@Wr+br (bf16 out) ----------------
__global__ __launch_bounds__(256) void proj_mfma(
    const short* __restrict__ xb, const short* __restrict__ WlT, const short* __restrict__ WrT,
    const float* __restrict__ bl, const float* __restrict__ br,
    short* __restrict__ xl, short* __restrict__ xr)
{
  __shared__ short As[64][40];
  int t = threadIdx.x;
  int wave = t >> 6, lane = t & 63;
  int lq = lane >> 4, lc = lane & 15;
  int row0 = blockIdx.x * 64;
  f32x4 accl[10] = {}, accr[10] = {};
  for (int kt = 0; kt < 5; ++kt) {
    int k0 = kt * 32;
    {
      int r = t >> 2, seg = t & 3;
      int gr = min(row0 + r, N_NODES - 1);
      bf16x8 v = *(const bf16x8*)&xb[(size_t)gr * 160 + k0 + seg * 8];
      *(bf16x8*)&As[r][seg * 8] = v;
    }
    __syncthreads();
    bf16x8 af = *(bf16x8*)&As[wave * 16 + lc][lq * 8];
#pragma unroll
    for (int ct = 0; ct < 10; ++ct) {
      int cc = ct * 16 + lc;
      bf16x8 bfl = *(const bf16x8*)&WlT[cc * 160 + k0 + lq * 8];
      accl[ct] = __builtin_amdgcn_mfma_f32_16x16x32_bf16(af, bfl, accl[ct], 0, 0, 0);
      bf16x8 bfr = *(const bf16x8*)&WrT[cc * 160 + k0 + lq * 8];
      accr[ct] = __builtin_amdgcn_mfma_f32_16x16x32_bf16(af, bfr, accr[ct], 0, 0, 0);
    }
    __syncthreads();
  }
#pragma unroll
  for (int ct = 0; ct < 10; ++ct) {
    int col = ct * 16 + lc;
    float bbl = bl[col], bbr = br[col];
#pragma unroll
    for (int rg = 0; rg < 4; ++rg) {
      int row = row0 + wave * 16 + lq * 4 + rg;
      if (row < N_NODES) {
        xl[(size_t)row * 160 + col] = f2bf(accl[ct][rg] + bbl);
        xr[(size_t)row * 160 + col] = f2bf(accr[ct][rg] + bbr);
      }
    }
  }
}

// ---------------- CSR build ----------------
__global__ void count_kernel(const int* __restrict__ ei, int* __restrict__ cnt) {
  int e = blockIdx.x * blockDim.x + threadIdx.x;
  if (e < E_EDGES) atomicAdd(&cnt[ei[E_EDGES + e]], 1);
}

// 3-kernel coalesced scan
__global__ __launch_bounds__(1024) void scanA(const int* __restrict__ cnt,
                                              int* __restrict__ pinc, int* __restrict__ bsum) {
  int b = blockIdx.x, t = threadIdx.x;
  int i = b * 1024 + t;
  int v = (i < N_NODES) ? cnt[i] : 0;
  int lane = t & 63, wid = t >> 6;
  int s = v;
#pragma unroll
  for (int off = 1; off < 64; off <<= 1) {
    int u = __shfl_up(s, off, 64);
    if (lane >= off) s += u;
  }
  __shared__ int ws[16];
  if (lane == 63) ws[wid] = s;
  __syncthreads();
  if (wid == 0) {
    int w = (lane < 16) ? ws[lane] : 0;
#pragma unroll
    for (int off = 1; off < 16; off <<= 1) {
      int u = __shfl_up(w, off, 64);
      if (lane >= off) w += u;
    }
    if (lane < 16) ws[lane] = w;
  }
  __syncthreads();
  int incl = s + (wid > 0 ? ws[wid - 1] : 0);
  if (i < N_NODES) pinc[i] = incl;
  if (t == 1023) bsum[b] = incl;
}

__global__ void scanB(const int* __restrict__ bsum, int* __restrict__ boff) {
  int t = threadIdx.x;   // one wave
  int v = (t < 49) ? bsum[t] : 0;
  int s = v;
#pragma unroll
  for (int off = 1; off < 64; off <<= 1) {
    int u = __shfl_up(s, off, 64);
    if (t >= off) s += u;
  }
  if (t < 49) boff[t] = s - v;
}

__global__ __launch_bounds__(1024) void scanC(const int* __restrict__ pinc,
                                              const int* __restrict__ boff,
                                              int* __restrict__ offs) {
  int b = blockIdx.x, t = threadIdx.x;
  int i = b * 1024 + t;
  if (i < N_NODES) offs[i + 1] = pinc[i] + boff[b];
  if (i == 0) offs[0] = 0;
}

// scatter: CSR-order src*160, bf16 edge_attr
__global__ void scatter3(const int* __restrict__ ei, const float* __restrict__ eattr,
                         const int* __restrict__ offs, int* __restrict__ cursor,
                         int* __restrict__ srcm, short* __restrict__ eacsr) {
  int e = blockIdx.x * blockDim.x + threadIdx.x;
  if (e < E_EDGES) {
    int dst = ei[E_EDGES + e];
    int src = ei[e];
    int slot = atomicAdd(&cursor[dst], 1);
    int j = offs[dst] + slot;
    srcm[j] = src * 160;
    const float4* s = (const float4*)&eattr[(size_t)e * ED];
    float4 v0 = s[0], v1 = s[1], v2 = s[2], v3 = s[3];
    short* o = eacsr + (size_t)j * ED;
    short4v w0, w1, w2, w3;
    w0[0]=f2bf(v0.x); w0[1]=f2bf(v0.y); w0[2]=f2bf(v0.z); w0[3]=f2bf(v0.w);
    w1[0]=f2bf(v1.x); w1[1]=f2bf(v1.y); w1[2]=f2bf(v1.z); w1[3]=f2bf(v1.w);
    w2[0]=f2bf(v2.x); w2[1]=f2bf(v2.y); w2[2]=f2bf(v2.z); w2[3]=f2bf(v2.w);
    w3[0]=f2bf(v3.x); w3[1]=f2bf(v3.y); w3[2]=f2bf(v3.z); w3[3]=f2bf(v3.w);
    *(short4v*)(o + 0) = w0; *(short4v*)(o + 4) = w1;
    *(short4v*)(o + 8) = w2; *(short4v*)(o + 12) = w3;
  }
}

// ---------------- fused attention: one wave per dst node ----------------
// Gather xl rows with full-wave 16B vector loads into a per-wave LDS tile
// (seg layout), then consume from LDS in MFMA col layout. 5 VMEM insts per
// 16-edge chunk instead of 40 scalar gathers.
__global__ __launch_bounds__(256) void attn_fused(
    const short* __restrict__ eacsr, const int* __restrict__ srcm,
    const short* __restrict__ WeTp, const short* __restrict__ xl, const short* __restrict__ xr,
    const float* __restrict__ att, const float* __restrict__ x,
    const float* __restrict__ b_gat, const float* __restrict__ g1, const float* __restrict__ b1,
    const int* __restrict__ offs,
    float* __restrict__ outb, short* __restrict__ outb_bf)
{
  __shared__ short xt[4][16][168];   // per-wave gather tile, padded rows (336 B)
  int t = threadIdx.x;
  int wave = t >> 6, lane = t & 63;
  int lq = lane >> 4, lc = lane & 15;
  int i = blockIdx.x * 4 + wave;     // dst node (grid*4 == N exactly)
  int e0 = offs[i], e1 = offs[i + 1];
  short* myt = &xt[wave][0][0];

  // per-lane seg mapping (constant over chunks): pass p covers global seg p*64+lane
  int segE[5], segS[5];
#pragma unroll
  for (int p = 0; p < 5; ++p) {
    int g = p * 64 + lane;
    int e = (g * 3277) >> 16;        // g / 20  (exact for g < 320)
    segE[p] = e;
    segS[p] = g - e * 20;            // g % 20
  }

  float aggc[10] = {};
  float den[5] = {};
  const f32x4 zero4 = {};

  for (int j0 = e0; j0 < e1; j0 += 16) {
    // --- gather 16 xl rows into LDS (seg layout, 5 full-wave b128 loads) ---
#pragma unroll
    for (int p = 0; p < 5; ++p) {
      int j = j0 + segE[p];
      if (j > e1 - 1) j = e1 - 1;
      int srow = srcm[j];            // src*160
      bf16x8 v = *(const bf16x8*)&xl[(size_t)srow + segS[p] * 8];
      *(bf16x8*)&myt[segE[p] * 168 + segS[p] * 8] = v;
    }
    // --- ea MFMA fragment (K=32, upper 16 zero-padded) ---
    bf16x8 af = {};
    if (lq < 2) {
      int jr = min(j0 + lc, e1 - 1);
      af = *(const bf16x8*)&eacsr[(size_t)jr * ED + lq * 8];
    }
    bool ok[4];
#pragma unroll
    for (int rg = 0; rg < 4; ++rg) ok[rg] = (j0 + lq * 4 + rg) < e1;

    float partial[5][4] = {};
#pragma unroll
    for (int half = 0; half < 2; ++half) {
      f32x4 acc[5];
#pragma unroll
      for (int cs = 0; cs < 5; ++cs) {
        int ct = half * 5 + cs;
        bf16x8 bfv = *(const bf16x8*)&WeTp[(ct * 16 + lc) * 32 + lq * 8];
        acc[cs] = __builtin_amdgcn_mfma_f32_16x16x32_bf16(af, bfv, zero4, 0, 0, 0);
      }
#pragma unroll
      for (int cs = 0; cs < 5; ++cs) {
        int ct = half * 5 + cs;
        int col = ct * 16 + lc;
        float attv = att[col];
        float xrv = bf2f(xr[(size_t)i * 160 + col]);
#pragma unroll
        for (int rg = 0; rg < 4; ++rg) {
          float xlv = bf2f(myt[(lq * 4 + rg) * 168 + col]);
          float z = acc[cs][rg] + xlv + xrv;
          z = fmaxf(z, NEG_SLOPE * z);
          partial[ct >> 1][rg] = fmaf(z, attv, partial[ct >> 1][rg]);
        }
      }
    }
    // reduce over 16 lc lanes -> per-(head, edge) score; exp (shift-invariant)
#pragma unroll
    for (int hh = 0; hh < 5; ++hh) {
#pragma unroll
      for (int rg = 0; rg < 4; ++rg) {
        float p = partial[hh][rg];
        p += __shfl_xor(p, 1, 64);
        p += __shfl_xor(p, 2, 64);
        p += __shfl_xor(p, 4, 64);
        p += __shfl_xor(p, 8, 64);
        float ex = ok[rg] ? __expf(p) : 0.f;
        den[hh] += ex;
        partial[hh][rg] = ex;        // reuse as ex
      }
    }
    // aggregate from LDS
#pragma unroll
    for (int ct = 0; ct < 10; ++ct) {
      int col = ct * 16 + lc;
#pragma unroll
      for (int rg = 0; rg < 4; ++rg) {
        float xlv = bf2f(myt[(lq * 4 + rg) * 168 + col]);
        aggc[ct] = fmaf(partial[ct >> 1][rg], xlv, aggc[ct]);
      }
    }
  }
  // combine the 4 lq edge-groups
#pragma unroll
  for (int ct = 0; ct < 10; ++ct) {
    aggc[ct] += __shfl_xor(aggc[ct], 16, 64);
    aggc[ct] += __shfl_xor(aggc[ct], 32, 64);
  }
#pragma unroll
  for (int hh = 0; hh < 5; ++hh) {
    den[hh] += __shfl_xor(den[hh], 16, 64);
    den[hh] += __shfl_xor(den[hh], 32, 64);
  }
  // residual + LN over 160 cols
  float val[10];
  float s1 = 0.f, s2 = 0.f;
#pragma unroll
  for (int ct = 0; ct < 10; ++ct) {
    float d = den[ct >> 1];
    float attn = (d > 0.f) ? aggc[ct] / d : 0.f;
    float v = x[(size_t)i * 160 + ct * 16 + lc] + attn + b_gat[ct * 16 + lc];
    val[ct] = v;
    s1 += v; s2 += v * v;
  }
#pragma unroll
  for (int m = 1; m <= 8; m <<= 1) { s1 += __shfl_xor(s1, m, 64); s2 += __shfl_xor(s2, m, 64); }
  float mu = s1 * (1.f / 160.f);
  float var = s2 * (1.f / 160.f) - mu * mu;
  float rstd = rsqrtf(var + EPS);
  if (lq == 0) {
#pragma unroll
    for (int ct = 0; ct < 10; ++ct) {
      int col = ct * 16 + lc;
      float o = (val[ct] - mu) * rstd * g1[col] + b1[col];
      outb[(size_t)i * 160 + col] = o;
      outb_bf[(size_t)i * 160 + col] = f2bf(o);
    }
  }
}

// ---------------- mlp1 MFMA: h = LN(selu(outb@Wm1+b)) -> bf16 ----------------
__global__ __launch_bounds__(256) void mlp1_mfma(
    const short* __restrict__ ab, const short* __restrict__ W1T,
    const float* __restrict__ b1m, const float* __restrict__ gm, const float* __restrict__ bm,
    short* __restrict__ h)
{
  __shared__ short As[32][40];
  __shared__ float ps1[4][32], ps2[4][32];
  int t = threadIdx.x;
  int wave = t >> 6, lane = t & 63;
  int lq = lane >> 4, lc = lane & 15;
  int row0 = blockIdx.x * 32;
  f32x4 acc[2][8] = {};
  for (int kt = 0; kt < 5; ++kt) {
    int k0 = kt * 32;
    if (t < 128) {
      int r = t >> 2, seg = t & 3;
      int gr = min(row0 + r, N_NODES - 1);
      bf16x8 v = *(const bf16x8*)&ab[(size_t)gr * 160 + k0 + seg * 8];
      *(bf16x8*)&As[r][seg * 8] = v;
    }
    __syncthreads();
    bf16x8 af0 = *(bf16x8*)&As[lc][lq * 8];
    bf16x8 af1 = *(bf16x8*)&As[16 + lc][lq * 8];
#pragma unroll
    for (int ct = 0; ct < 8; ++ct) {
      int cc = wave * 128 + ct * 16 + lc;
      bf16x8 bfv = *(const bf16x8*)&W1T[cc * 160 + k0 + lq * 8];
      acc[0][ct] = __builtin_amdgcn_mfma_f32_16x16x32_bf16(af0, bfv, acc[0][ct], 0, 0, 0);
      acc[1][ct] = __builtin_amdgcn_mfma_f32_16x16x32_bf16(af1, bfv, acc[1][ct], 0, 0, 0);
    }
    __syncthreads();
  }
  float s1[2][4] = {}, s2[2][4] = {};
#pragma unroll
  for (int rt = 0; rt < 2; ++rt)
#pragma unroll
    for (int ct = 0; ct < 8; ++ct)
#pragma unroll
      for (int rg = 0; rg < 4; ++rg) {
        int cc = wave * 128 + ct * 16 + lc;
        float v = selu_f(acc[rt][ct][rg] + b1m[cc]);
        acc[rt][ct][rg] = v;
        s1[rt][rg] += v; s2[rt][rg] += v * v;
      }
#pragma unroll
  for (int m = 1; m <= 8; m <<= 1) {
#pragma unroll
    for (int rt = 0; rt < 2; ++rt)
#pragma unroll
      for (int rg = 0; rg < 4; ++rg) {
        s1[rt][rg] += __shfl_xor(s1[rt][rg], m, 64);
        s2[rt][rg] += __shfl_xor(s2[rt][rg], m, 64);
      }
  }
  if (lc == 0) {
#pragma unroll
    for (int rt = 0; rt < 2; ++rt)
#pragma unroll
      for (int rg = 0; rg < 4; ++rg) {
        ps1[wave][rt * 16 + lq * 4 + rg] = s1[rt][rg];
        ps2[wave][rt * 16 + lq * 4 + rg] = s2[rt][rg];
      }
  }
  __syncthreads();
  float mu[2][4], rstd[2][4];
#pragma unroll
  for (int rt = 0; rt < 2; ++rt)
#pragma unroll
    for (int rg = 0; rg < 4; ++rg) {
      int rl = rt * 16 + lq * 4 + rg;
      float a = ps1[0][rl] + ps1[1][rl] + ps1[2][rl] + ps1[3][rl];
      float b = ps2[0][rl] + ps2[1][rl] + ps2[2][rl] + ps2[3][rl];
      float m_ = a * (1.f / 512.f);
      float var = b * (1.f / 512.f) - m_ * m_;
      mu[rt][rg] = m_; rstd[rt][rg] = rsqrtf(var + EPS);
    }
#pragma unroll
  for (int rt = 0; rt < 2; ++rt)
#pragma unroll
    for (int ct = 0; ct < 8; ++ct)
#pragma unroll
      for (int rg = 0; rg < 4; ++rg) {
        int row = row0 + rt * 16 + lq * 4 + rg;
        int cc = wave * 128 + ct * 16 + lc;
        if (row < N_NODES)
          h[(size_t)row * 512 + cc] =
              f2bf((acc[rt][ct][rg] - mu[rt][rg]) * rstd[rt][rg] * gm[cc] + bm[cc]);
      }
}

// ---------------- mlp2 MFMA: y = LN(outb + h@Wm2 + b) ----------------
__global__ __launch_bounds__(256) void mlp2_mfma(
    const short* __restrict__ hb, const short* __restrict__ W2T,
    const float* __restrict__ b2m, const float* __restrict__ outb,
    const float* __restrict__ g2, const float* __restrict__ b2,
    float* __restrict__ y)
{
  __shared__ short As[128][72];
  int t = threadIdx.x;
  int wave = t >> 6, lane = t & 63;
  int lq = lane >> 4, lc = lane & 15;
  int row0 = blockIdx.x * 128;
  f32x4 acc[2][10] = {};
  for (int kt = 0; kt < 8; ++kt) {
    int k0 = kt * 64;
    __syncthreads();
#pragma unroll
    for (int q = 0; q < 4; ++q) {
      int idx = t + 256 * q;
      int r = idx >> 3, seg = idx & 7;
      int gr = min(row0 + r, N_NODES - 1);
      *(bf16x8*)&As[r][seg * 8] = *(const bf16x8*)&hb[(size_t)gr * 512 + k0 + seg * 8];
    }
    __syncthreads();
#pragma unroll
    for (int ks = 0; ks < 2; ++ks) {
      bf16x8 af0 = *(bf16x8*)&As[wave * 32 + lc][ks * 32 + lq * 8];
      bf16x8 af1 = *(bf16x8*)&As[wave * 32 + 16 + lc][ks * 32 + lq * 8];
#pragma unroll
      for (int ct = 0; ct < 10; ++ct) {
        bf16x8 bfv = *(const bf16x8*)&W2T[(ct * 16 + lc) * 512 + k0 + ks * 32 + lq * 8];
        acc[0][ct] = __builtin_amdgcn_mfma_f32_16x16x32_bf16(af0, bfv, acc[0][ct], 0, 0, 0);
        acc[1][ct] = __builtin_amdgcn_mfma_f32_16x16x32_bf16(af1, bfv, acc[1][ct], 0, 0, 0);
      }
    }
  }
  float s1[2][4] = {}, s2[2][4] = {};
#pragma unroll
  for (int rt = 0; rt < 2; ++rt)
#pragma unroll
    for (int ct = 0; ct < 10; ++ct) {
      int col = ct * 16 + lc;
#pragma unroll
      for (int rg = 0; rg < 4; ++rg) {
        int rowl = min(row0 + wave * 32 + rt * 16 + lq * 4 + rg, N_NODES - 1);
        float v = acc[rt][ct][rg] + b2m[col] + outb[(size_t)rowl * 160 + col];
        acc[rt][ct][rg] = v;
        s1[rt][rg] += v; s2[rt][rg] += v * v;
      }
    }
#pragma unroll
  for (int m = 1; m <= 8; m <<= 1) {
#pragma unroll
    for (int rt = 0; rt < 2; ++rt)
#pragma unroll
      for (int rg = 0; rg < 4; ++rg) {
        s1[rt][rg] += __shfl_xor(s1[rt][rg], m, 64);
        s2[rt][rg] += __shfl_xor(s2[rt][rg], m, 64);
      }
  }
  float mu[2][4], rstd[2][4];
#pragma unroll
  for (int rt = 0; rt < 2; ++rt)
#pragma unroll
    for (int rg = 0; rg < 4; ++rg) {
      float m_ = s1[rt][rg] * (1.f / 160.f);
      float var = s2[rt][rg] * (1.f / 160.f) - m_ * m_;
      mu[rt][rg] = m_; rstd[rt][rg] = rsqrtf(var + EPS);
    }
#pragma unroll
  for (int rt = 0; rt < 2; ++rt)
#pragma unroll
    for (int ct = 0; ct < 10; ++ct) {
      int col = ct * 16 + lc;
#pragma unroll
      for (int rg = 0; rg < 4; ++rg) {
        int row = row0 + wave * 32 + rt * 16 + lq * 4 + rg;
        if (row < N_NODES)
          y[(size_t)row * 160 + col] = (acc[rt][ct][rg] - mu[rt][rg]) * rstd[rt][rg] * g2[col] + b2[col];
      }
    }
}

extern "C" void kernel_launch(void* const* d_in, const int* in_sizes, int n_in,
                              void* d_out, int out_size, void* d_ws, size_t ws_size,
                              hipStream_t stream) {
  const float* x     = (const float*)d_in[0];
  const int*   ei    = (const int*)d_in[1];
  const float* eattr = (const float*)d_in[2];
  const float* Wl    = (const float*)d_in[5];
  const float* bl    = (const float*)d_in[6];
  const float* Wr    = (const float*)d_in[7];
  const float* br    = (const float*)d_in[8];
  const float* We    = (const float*)d_in[9];
  const float* att   = (const float*)d_in[10];
  const float* bgat  = (const float*)d_in[11];
  const float* g1    = (const float*)d_in[12];
  const float* b1    = (const float*)d_in[13];
  const float* Wm1   = (const float*)d_in[14];
  const float* bm1   = (const float*)d_in[15];
  const float* gm    = (const float*)d_in[16];
  const float* bm    = (const float*)d_in[17];
  const float* Wm2   = (const float*)d_in[18];
  const float* bm2   = (const float*)d_in[19];
  const float* g2    = (const float*)d_in[20];
  const float* b2    = (const float*)d_in[21];
  float* y = (float*)d_out;

  char* p = (char*)d_ws;
  auto alloc = [&](size_t bytes) {
    void* q = p;
    p += (bytes + 255) & ~(size_t)255;
    return q;
  };
  short* xb      = (short*)alloc((size_t)N_NODES * 160 * 2);
  short* xlb     = (short*)alloc((size_t)N_NODES * 160 * 2);
  short* xrb     = (short*)alloc((size_t)N_NODES * 160 * 2);
  float* outb    = (float*)alloc((size_t)N_NODES * 160 * 4);
  short* outb_bf = (short*)alloc((size_t)N_NODES * 160 * 2);
  short* hb      = (short*)alloc((size_t)N_NODES * 512 * 2);
  short* eacsr   = (short*)alloc((size_t)E_EDGES * ED * 2);
  int*   srcm    = (int*)alloc((size_t)E_EDGES * 4);
  short* WlT     = (short*)alloc(160 * 160 * 2);
  short* WrT     = (short*)alloc(160 * 160 * 2);
  short* W1T     = (short*)alloc(512 * 160 * 2);
  short* W2T     = (short*)alloc(160 * 512 * 2);
  short* WeTp    = (short*)alloc(160 * 32 * 2);
  int*   cnt     = (int*)alloc((size_t)N_NODES * 4);
  int*   offs    = (int*)alloc((size_t)(N_NODES + 1) * 4);
  int*   cursor  = (int*)alloc((size_t)N_NODES * 4);
  int*   pinc    = (int*)alloc((size_t)N_NODES * 4);
  int*   bsum    = (int*)alloc(64 * 4);
  int*   boff    = (int*)alloc(64 * 4);

  hipMemsetAsync(cnt, 0, (size_t)N_NODES * 4, stream);
  hipMemsetAsync(cursor, 0, (size_t)N_NODES * 4, stream);

  prep_weights<<<(220160 + 255) / 256, 256, 0, stream>>>(Wl, Wr, Wm1, Wm2, We,
                                                         WlT, WrT, W1T, W2T, WeTp);
  convert_x<<<(N_NODES * 160 / 8 + 255) / 256, 256, 0, stream>>>(x, xb);
  count_kernel<<<(E_EDGES + 255) / 256, 256, 0, stream>>>(ei, cnt);
  scanA<<<49, 1024, 0, stream>>>(cnt, pinc, bsum);
  scanB<<<1, 64, 0, stream>>>(bsum, boff);
  scanC<<<49, 1024, 0, stream>>>(pinc, boff, offs);
  scatter3<<<(E_EDGES + 255) / 256, 256, 0, stream>>>(ei, eattr, offs, cursor, srcm, eacsr);
  proj_mfma<<<(N_NODES + 63) / 64, 256, 0, stream>>>(xb, WlT, WrT, bl, br, xlb, xrb);
  attn_fused<<<N_NODES / 4, 256, 0, stream>>>(eacsr, srcm, WeTp, xlb, xrb, att, x,
                                              bgat, g1, b1, offs, outb, outb_bf);
  mlp1_mfma<<<(N_NODES + 31) / 32, 256, 0, stream>>>(outb_bf, W1T, bm1, gm, bm, hb);
  mlp2_mfma<<<(N_NODES + 127) / 128, 256, 0, stream>>>(hb, W2T, bm2, outb, g2, b2, y);
}

// Round 6
// 670.289 us; speedup vs baseline: 1.2111x; 1.0103x over previous
//
#include <hip/hip_runtime.h>
#include <math.h>

#define N_NODES 50000
#define D 160
#define H 5
#define C 32
#define HC 160
#define E_EDGES 800000
#define ED 16
#define HID 512
#define EPS 1e-5f
#define NEG_SLOPE 0.2f

typedef __attribute__((ext_vector_type(8))) short bf16x8;
typedef __attribute__((ext_vector_type(4))) float f32x4;
typedef __attribute__((ext_vector_type(4))) short short4v;

__device__ inline float bf2f(short s) {
  unsigned u = ((unsigned)(unsigned short)s) << 16;
  return __builtin_bit_cast(float, u);
}
__device__ inline short f2bf(float f) {
  unsigned u = __builtin_bit_cast(unsigned, f);
  u = u + 0x7fffu + ((u >> 16) & 1u);
  return (short)(u >> 16);
}
__device__ inline float selu_f(float v) {
  return 1.0507009873554805f * (v > 0.f ? v : 1.6732632423543772f * (__expf(v) - 1.f));
}

// ---------------- weight prep: transpose + bf16 (+ padded WeT) ----------------
__global__ void prep_weights(const float* __restrict__ Wl, const float* __restrict__ Wr,
                             const float* __restrict__ Wm1, const float* __restrict__ Wm2,
                             const float* __restrict__ We,
                             short* __restrict__ WlT, short* __restrict__ WrT,
                             short* __restrict__ W1T, short* __restrict__ W2T,
                             short* __restrict__ WeTp) {
  int i = blockIdx.x * blockDim.x + threadIdx.x;
  if (i < 25600) { int n = i / 160, k = i % 160; WlT[n*160 + k] = f2bf(Wl[k*160 + n]); return; }
  i -= 25600;
  if (i < 25600) { int n = i / 160, k = i % 160; WrT[n*160 + k] = f2bf(Wr[k*160 + n]); return; }
  i -= 25600;
  if (i < 81920) { int n = i / 160, k = i % 160; W1T[n*160 + k] = f2bf(Wm1[k*512 + n]); return; }
  i -= 81920;
  if (i < 81920) { int n = i / 512, k = i % 512; W2T[n*512 + k] = f2bf(Wm2[k*160 + n]); return; }
  i -= 81920;
  if (i < 5120) { int col = i / 32, k = i % 32;
    WeTp[col*32 + k] = (k < ED) ? f2bf(We[k*160 + col]) : (short)0; }
}

// ---------------- proj: xl = x@Wl+bl, xr = x@Wr+br (fp32 in, bf16 out) ----------
// No LDS, no barriers: each wave owns 16 rows; A fragments loaded fp32 direct
// from global and converted in-reg. grid*4waves*16rows >= N.
__global__ __launch_bounds__(256) void proj_mfma(
    const float* __restrict__ x, const short* __restrict__ WlT, const short* __restrict__ WrT,
    const float* __restrict__ bl, const float* __restrict__ br,
    short* __restrict__ xl, short* __restrict__ xr)
{
  int t = threadIdx.x;
  int wave = t >> 6, lane = t & 63;
  int lq = lane >> 4, lc = lane & 15;
  int row0 = blockIdx.x * 64 + wave * 16;
  f32x4 accl[10] = {}, accr[10] = {};
#pragma unroll
  for (int kt = 0; kt < 5; ++kt) {
    int gr = min(row0 + lc, N_NODES - 1);
    const float4* pa = (const float4*)&x[(size_t)gr * 160 + kt * 32 + lq * 8];
    float4 a0 = pa[0], a1 = pa[1];
    bf16x8 af;
    af[0] = f2bf(a0.x); af[1] = f2bf(a0.y); af[2] = f2bf(a0.z); af[3] = f2bf(a0.w);
    af[4] = f2bf(a1.x); af[5] = f2bf(a1.y); af[6] = f2bf(a1.z); af[7] = f2bf(a1.w);
#pragma unroll
    for (int ct = 0; ct < 10; ++ct) {
      int cc = ct * 16 + lc;
      bf16x8 bfl = *(const bf16x8*)&WlT[cc * 160 + kt * 32 + lq * 8];
      accl[ct] = __builtin_amdgcn_mfma_f32_16x16x32_bf16(af, bfl, accl[ct], 0, 0, 0);
      bf16x8 bfr = *(const bf16x8*)&WrT[cc * 160 + kt * 32 + lq * 8];
      accr[ct] = __builtin_amdgcn_mfma_f32_16x16x32_bf16(af, bfr, accr[ct], 0, 0, 0);
    }
  }
#pragma unroll
  for (int ct = 0; ct < 10; ++ct) {
    int col = ct * 16 + lc;
    float bbl = bl[col], bbr = br[col];
#pragma unroll
    for (int rg = 0; rg < 4; ++rg) {
      int row = row0 + lq * 4 + rg;
      if (row < N_NODES) {
        xl[(size_t)row * 160 + col] = f2bf(accl[ct][rg] + bbl);
        xr[(size_t)row * 160 + col] = f2bf(accr[ct][rg] + bbr);
      }
    }
  }
}

// ---------------- CSR build ----------------
__global__ void count_kernel(const int* __restrict__ ei, int* __restrict__ cnt) {
  int e = blockIdx.x * blockDim.x + threadIdx.x;
  if (e < E_EDGES) atomicAdd(&cnt[ei[E_EDGES + e]], 1);
}

__global__ __launch_bounds__(1024) void scanA(const int* __restrict__ cnt,
                                              int* __restrict__ pinc, int* __restrict__ bsum) {
  int b = blockIdx.x, t = threadIdx.x;
  int i = b * 1024 + t;
  int v = (i < N_NODES) ? cnt[i] : 0;
  int lane = t & 63, wid = t >> 6;
  int s = v;
#pragma unroll
  for (int off = 1; off < 64; off <<= 1) {
    int u = __shfl_up(s, off, 64);
    if (lane >= off) s += u;
  }
  __shared__ int ws[16];
  if (lane == 63) ws[wid] = s;
  __syncthreads();
  if (wid == 0) {
    int w = (lane < 16) ? ws[lane] : 0;
#pragma unroll
    for (int off = 1; off < 16; off <<= 1) {
      int u = __shfl_up(w, off, 64);
      if (lane >= off) w += u;
    }
    if (lane < 16) ws[lane] = w;
  }
  __syncthreads();
  int incl = s + (wid > 0 ? ws[wid - 1] : 0);
  if (i < N_NODES) pinc[i] = incl;
  if (t == 1023) bsum[b] = incl;
}

__global__ void scanB(const int* __restrict__ bsum, int* __restrict__ boff) {
  int t = threadIdx.x;
  int v = (t < 49) ? bsum[t] : 0;
  int s = v;
#pragma unroll
  for (int off = 1; off < 64; off <<= 1) {
    int u = __shfl_up(s, off, 64);
    if (t >= off) s += u;
  }
  if (t < 49) boff[t] = s - v;
}

__global__ __launch_bounds__(1024) void scanC(const int* __restrict__ pinc,
                                              const int* __restrict__ boff,
                                              int* __restrict__ offs) {
  int b = blockIdx.x, t = threadIdx.x;
  int i = b * 1024 + t;
  if (i < N_NODES) offs[i + 1] = pinc[i] + boff[b];
  if (i == 0) offs[0] = 0;
}

// scatter: CSR-order src*160, bf16 edge_attr
__global__ void scatter3(const int* __restrict__ ei, const float* __restrict__ eattr,
                         const int* __restrict__ offs, int* __restrict__ cursor,
                         int* __restrict__ srcm, short* __restrict__ eacsr) {
  int e = blockIdx.x * blockDim.x + threadIdx.x;
  if (e < E_EDGES) {
    int dst = ei[E_EDGES + e];
    int src = ei[e];
    int slot = atomicAdd(&cursor[dst], 1);
    int j = offs[dst] + slot;
    srcm[j] = src * 160;
    const float4* s = (const float4*)&eattr[(size_t)e * ED];
    float4 v0 = s[0], v1 = s[1], v2 = s[2], v3 = s[3];
    short* o = eacsr + (size_t)j * ED;
    short4v w0, w1, w2, w3;
    w0[0]=f2bf(v0.x); w0[1]=f2bf(v0.y); w0[2]=f2bf(v0.z); w0[3]=f2bf(v0.w);
    w1[0]=f2bf(v1.x); w1[1]=f2bf(v1.y); w1[2]=f2bf(v1.z); w1[3]=f2bf(v1.w);
    w2[0]=f2bf(v2.x); w2[1]=f2bf(v2.y); w2[2]=f2bf(v2.z); w2[3]=f2bf(v2.w);
    w3[0]=f2bf(v3.x); w3[1]=f2bf(v3.y); w3[2]=f2bf(v3.z); w3[3]=f2bf(v3.w);
    *(short4v*)(o + 0) = w0; *(short4v*)(o + 4) = w1;
    *(short4v*)(o + 8) = w2; *(short4v*)(o + 12) = w3;
  }
}

// ---------------- fused attention: one wave per dst node ----------------
__global__ __launch_bounds__(256) void attn_fused(
    const short* __restrict__ eacsr, const int* __restrict__ srcm,
    const short* __restrict__ WeTp, const short* __restrict__ xl, const short* __restrict__ xr,
    const float* __restrict__ att, const float* __restrict__ x,
    const float* __restrict__ b_gat, const float* __restrict__ g1, const float* __restrict__ b1,
    const int* __restrict__ offs,
    float* __restrict__ outb, short* __restrict__ outb_bf)
{
  __shared__ short xt[4][16][168];
  int t = threadIdx.x;
  int wave = t >> 6, lane = t & 63;
  int lq = lane >> 4, lc = lane & 15;
  int i = blockIdx.x * 4 + wave;
  int e0 = offs[i], e1 = offs[i + 1];
  short* myt = &xt[wave][0][0];

  int segE[5], segS[5];
#pragma unroll
  for (int p = 0; p < 5; ++p) {
    int g = p * 64 + lane;
    int e = (g * 3277) >> 16;
    segE[p] = e;
    segS[p] = g - e * 20;
  }

  float aggc[10] = {};
  float den[5] = {};
  const f32x4 zero4 = {};

  for (int j0 = e0; j0 < e1; j0 += 16) {
#pragma unroll
    for (int p = 0; p < 5; ++p) {
      int j = j0 + segE[p];
      if (j > e1 - 1) j = e1 - 1;
      int srow = srcm[j];
      bf16x8 v = *(const bf16x8*)&xl[(size_t)srow + segS[p] * 8];
      *(bf16x8*)&myt[segE[p] * 168 + segS[p] * 8] = v;
    }
    bf16x8 af = {};
    if (lq < 2) {
      int jr = min(j0 + lc, e1 - 1);
      af = *(const bf16x8*)&eacsr[(size_t)jr * ED + lq * 8];
    }
    bool ok[4];
#pragma unroll
    for (int rg = 0; rg < 4; ++rg) ok[rg] = (j0 + lq * 4 + rg) < e1;

    float partial[5][4] = {};
#pragma unroll
    for (int half = 0; half < 2; ++half) {
      f32x4 acc[5];
#pragma unroll
      for (int cs = 0; cs < 5; ++cs) {
        int ct = half * 5 + cs;
        bf16x8 bfv = *(const bf16x8*)&WeTp[(ct * 16 + lc) * 32 + lq * 8];
        acc[cs] = __builtin_amdgcn_mfma_f32_16x16x32_bf16(af, bfv, zero4, 0, 0, 0);
      }
#pragma unroll
      for (int cs = 0; cs < 5; ++cs) {
        int ct = half * 5 + cs;
        int col = ct * 16 + lc;
        float attv = att[col];
        float xrv = bf2f(xr[(size_t)i * 160 + col]);
#pragma unroll
        for (int rg = 0; rg < 4; ++rg) {
          float xlv = bf2f(myt[(lq * 4 + rg) * 168 + col]);
          float z = acc[cs][rg] + xlv + xrv;
          z = fmaxf(z, NEG_SLOPE * z);
          partial[ct >> 1][rg] = fmaf(z, attv, partial[ct >> 1][rg]);
        }
      }
    }
#pragma unroll
    for (int hh = 0; hh < 5; ++hh) {
#pragma unroll
      for (int rg = 0; rg < 4; ++rg) {
        float p = partial[hh][rg];
        p += __shfl_xor(p, 1, 64);
        p += __shfl_xor(p, 2, 64);
        p += __shfl_xor(p, 4, 64);
        p += __shfl_xor(p, 8, 64);
        float ex = ok[rg] ? __expf(p) : 0.f;
        den[hh] += ex;
        partial[hh][rg] = ex;
      }
    }
#pragma unroll
    for (int ct = 0; ct < 10; ++ct) {
      int col = ct * 16 + lc;
#pragma unroll
      for (int rg = 0; rg < 4; ++rg) {
        float xlv = bf2f(myt[(lq * 4 + rg) * 168 + col]);
        aggc[ct] = fmaf(partial[ct >> 1][rg], xlv, aggc[ct]);
      }
    }
  }
#pragma unroll
  for (int ct = 0; ct < 10; ++ct) {
    aggc[ct] += __shfl_xor(aggc[ct], 16, 64);
    aggc[ct] += __shfl_xor(aggc[ct], 32, 64);
  }
#pragma unroll
  for (int hh = 0; hh < 5; ++hh) {
    den[hh] += __shfl_xor(den[hh], 16, 64);
    den[hh] += __shfl_xor(den[hh], 32, 64);
  }
  float val[10];
  float s1 = 0.f, s2 = 0.f;
#pragma unroll
  for (int ct = 0; ct < 10; ++ct) {
    float d = den[ct >> 1];
    float attn = (d > 0.f) ? aggc[ct] / d : 0.f;
    float v = x[(size_t)i * 160 + ct * 16 + lc] + attn + b_gat[ct * 16 + lc];
    val[ct] = v;
    s1 += v; s2 += v * v;
  }
#pragma unroll
  for (int m = 1; m <= 8; m <<= 1) { s1 += __shfl_xor(s1, m, 64); s2 += __shfl_xor(s2, m, 64); }
  float mu = s1 * (1.f / 160.f);
  float var = s2 * (1.f / 160.f) - mu * mu;
  float rstd = rsqrtf(var + EPS);
  if (lq == 0) {
#pragma unroll
    for (int ct = 0; ct < 10; ++ct) {
      int col = ct * 16 + lc;
      float o = (val[ct] - mu) * rstd * g1[col] + b1[col];
      outb[(size_t)i * 160 + col] = o;
      outb_bf[(size_t)i * 160 + col] = f2bf(o);
    }
  }
}

// ---------------- mlp1: h = LN(selu(outb@Wm1+b)) -> bf16 ----------------
// 16 rows/block, 4 waves x 128 cols. A fragments direct from global.
// Single barrier pair for the cross-wave LN(512) exchange.
__global__ __launch_bounds__(256) void mlp1_mfma(
    const short* __restrict__ ab, const short* __restrict__ W1T,
    const float* __restrict__ b1m, const float* __restrict__ gm, const float* __restrict__ bm,
    short* __restrict__ h)
{
  __shared__ float ps1[4][16], ps2[4][16];
  int t = threadIdx.x;
  int wave = t >> 6, lane = t & 63;
  int lq = lane >> 4, lc = lane & 15;
  int row0 = blockIdx.x * 16;          // grid 3125 * 16 = 50000 exact
  f32x4 acc[8] = {};
#pragma unroll
  for (int kt = 0; kt < 5; ++kt) {
    bf16x8 af = *(const bf16x8*)&ab[(size_t)(row0 + lc) * 160 + kt * 32 + lq * 8];
#pragma unroll
    for (int ct = 0; ct < 8; ++ct) {
      int cc = wave * 128 + ct * 16 + lc;
      bf16x8 bfv = *(const bf16x8*)&W1T[cc * 160 + kt * 32 + lq * 8];
      acc[ct] = __builtin_amdgcn_mfma_f32_16x16x32_bf16(af, bfv, acc[ct], 0, 0, 0);
    }
  }
  float s1[4] = {}, s2[4] = {};
#pragma unroll
  for (int ct = 0; ct < 8; ++ct) {
    int cc = wave * 128 + ct * 16 + lc;
    float bb = b1m[cc];
#pragma unroll
    for (int rg = 0; rg < 4; ++rg) {
      float v = selu_f(acc[ct][rg] + bb);
      acc[ct][rg] = v;
      s1[rg] += v; s2[rg] += v * v;
    }
  }
#pragma unroll
  for (int m = 1; m <= 8; m <<= 1) {
#pragma unroll
    for (int rg = 0; rg < 4; ++rg) {
      s1[rg] += __shfl_xor(s1[rg], m, 64);
      s2[rg] += __shfl_xor(s2[rg], m, 64);
    }
  }
  if (lc == 0) {
#pragma unroll
    for (int rg = 0; rg < 4; ++rg) {
      ps1[wave][lq * 4 + rg] = s1[rg];
      ps2[wave][lq * 4 + rg] = s2[rg];
    }
  }
  __syncthreads();
  float mu[4], rstd[4];
#pragma unroll
  for (int rg = 0; rg < 4; ++rg) {
    int rl = lq * 4 + rg;
    float a = ps1[0][rl] + ps1[1][rl] + ps1[2][rl] + ps1[3][rl];
    float b = ps2[0][rl] + ps2[1][rl] + ps2[2][rl] + ps2[3][rl];
    float m_ = a * (1.f / 512.f);
    float var = b * (1.f / 512.f) - m_ * m_;
    mu[rg] = m_; rstd[rg] = rsqrtf(var + EPS);
  }
#pragma unroll
  for (int ct = 0; ct < 8; ++ct) {
    int cc = wave * 128 + ct * 16 + lc;
    float gg = gm[cc], bb = bm[cc];
#pragma unroll
    for (int rg = 0; rg < 4; ++rg) {
      int row = row0 + lq * 4 + rg;
      h[(size_t)row * 512 + cc] = f2bf((acc[ct][rg] - mu[rg]) * rstd[rg] * gg + bb);
    }
  }
}

// ---------------- mlp2: y = LN(outb + h@Wm2 + b) ----------------
// 16 rows/wave, 64 rows/block; A direct from global, no LDS, no barriers.
__global__ __launch_bounds__(256) void mlp2_mfma(
    const short* __restrict__ hb, const short* __restrict__ W2T,
    const float* __restrict__ b2m, const float* __restrict__ outb,
    const float* __restrict__ g2, const float* __restrict__ b2,
    float* __restrict__ y)
{
  int t = threadIdx.x;
  int wave = t >> 6, lane = t & 63;
  int lq = lane >> 4, lc = lane & 15;
  int row0 = blockIdx.x * 64 + wave * 16;
  f32x4 acc[10] = {};
#pragma unroll
  for (int kt = 0; kt < 16; ++kt) {
    int gr = min(row0 + lc, N_NODES - 1);
    bf16x8 af = *(const bf16x8*)&hb[(size_t)gr * 512 + kt * 32 + lq * 8];
#pragma unroll
    for (int ct = 0; ct < 10; ++ct) {
      bf16x8 bfv = *(const bf16x8*)&W2T[(ct * 16 + lc) * 512 + kt * 32 + lq * 8];
      acc[ct] = __builtin_amdgcn_mfma_f32_16x16x32_bf16(af, bfv, acc[ct], 0, 0, 0);
    }
  }
  float s1[4] = {}, s2[4] = {};
#pragma unroll
  for (int ct = 0; ct < 10; ++ct) {
    int col = ct * 16 + lc;
#pragma unroll
    for (int rg = 0; rg < 4; ++rg) {
      int rowl = min(row0 + lq * 4 + rg, N_NODES - 1);
      float v = acc[ct][rg] + b2m[col] + outb[(size_t)rowl * 160 + col];
      acc[ct][rg] = v;
      s1[rg] += v; s2[rg] += v * v;
    }
  }
#pragma unroll
  for (int m = 1; m <= 8; m <<= 1) {
#pragma unroll
    for (int rg = 0; rg < 4; ++rg) {
      s1[rg] += __shfl_xor(s1[rg], m, 64);
      s2[rg] += __shfl_xor(s2[rg], m, 64);
    }
  }
  float mu[4], rstd[4];
#pragma unroll
  for (int rg = 0; rg < 4; ++rg) {
    float m_ = s1[rg] * (1.f / 160.f);
    float var = s2[rg] * (1.f / 160.f) - m_ * m_;
    mu[rg] = m_; rstd[rg] = rsqrtf(var + EPS);
  }
#pragma unroll
  for (int ct = 0; ct < 10; ++ct) {
    int col = ct * 16 + lc;
#pragma unroll
    for (int rg = 0; rg < 4; ++rg) {
      int row = row0 + lq * 4 + rg;
      if (row < N_NODES)
        y[(size_t)row * 160 + col] = (acc[ct][rg] - mu[rg]) * rstd[rg] * g2[col] + b2[col];
    }
  }
}

extern "C" void kernel_launch(void* const* d_in, const int* in_sizes, int n_in,
                              void* d_out, int out_size, void* d_ws, size_t ws_size,
                              hipStream_t stream) {
  const float* x     = (const float*)d_in[0];
  const int*   ei    = (const int*)d_in[1];
  const float* eattr = (const float*)d_in[2];
  const float* Wl    = (const float*)d_in[5];
  const float* bl    = (const float*)d_in[6];
  const float* Wr    = (const float*)d_in[7];
  const float* br    = (const float*)d_in[8];
  const float* We    = (const float*)d_in[9];
  const float* att   = (const float*)d_in[10];
  const float* bgat  = (const float*)d_in[11];
  const float* g1    = (const float*)d_in[12];
  const float* b1    = (const float*)d_in[13];
  const float* Wm1   = (const float*)d_in[14];
  const float* bm1   = (const float*)d_in[15];
  const float* gm    = (const float*)d_in[16];
  const float* bm    = (const float*)d_in[17];
  const float* Wm2   = (const float*)d_in[18];
  const float* bm2   = (const float*)d_in[19];
  const float* g2    = (const float*)d_in[20];
  const float* b2    = (const float*)d_in[21];
  float* y = (float*)d_out;

  char* p = (char*)d_ws;
  auto alloc = [&](size_t bytes) {
    void* q = p;
    p += (bytes + 255) & ~(size_t)255;
    return q;
  };
  short* xlb     = (short*)alloc((size_t)N_NODES * 160 * 2);
  short* xrb     = (short*)alloc((size_t)N_NODES * 160 * 2);
  float* outb    = (float*)alloc((size_t)N_NODES * 160 * 4);
  short* outb_bf = (short*)alloc((size_t)N_NODES * 160 * 2);
  short* hb      = (short*)alloc((size_t)N_NODES * 512 * 2);
  short* eacsr   = (short*)alloc((size_t)E_EDGES * ED * 2);
  int*   srcm    = (int*)alloc((size_t)E_EDGES * 4);
  short* WlT     = (short*)alloc(160 * 160 * 2);
  short* WrT     = (short*)alloc(160 * 160 * 2);
  short* W1T     = (short*)alloc(512 * 160 * 2);
  short* W2T     = (short*)alloc(160 * 512 * 2);
  short* WeTp    = (short*)alloc(160 * 32 * 2);
  int*   cnt     = (int*)alloc((size_t)N_NODES * 4);
  int*   offs    = (int*)alloc((size_t)(N_NODES + 1) * 4);
  int*   cursor  = (int*)alloc((size_t)N_NODES * 4);
  int*   pinc    = (int*)alloc((size_t)N_NODES * 4);
  int*   bsum    = (int*)alloc(64 * 4);
  int*   boff    = (int*)alloc(64 * 4);

  hipMemsetAsync(cnt, 0, (size_t)N_NODES * 4, stream);
  hipMemsetAsync(cursor, 0, (size_t)N_NODES * 4, stream);

  prep_weights<<<(220160 + 255) / 256, 256, 0, stream>>>(Wl, Wr, Wm1, Wm2, We,
                                                         WlT, WrT, W1T, W2T, WeTp);
  count_kernel<<<(E_EDGES + 255) / 256, 256, 0, stream>>>(ei, cnt);
  scanA<<<49, 1024, 0, stream>>>(cnt, pinc, bsum);
  scanB<<<1, 64, 0, stream>>>(bsum, boff);
  scanC<<<49, 1024, 0, stream>>>(pinc, boff, offs);
  scatter3<<<(E_EDGES + 255) / 256, 256, 0, stream>>>(ei, eattr, offs, cursor, srcm, eacsr);
  proj_mfma<<<(N_NODES + 63) / 64, 256, 0, stream>>>(x, WlT, WrT, bl, br, xlb, xrb);
  attn_fused<<<N_NODES / 4, 256, 0, stream>>>(eacsr, srcm, WeTp, xlb, xrb, att, x,
                                              bgat, g1, b1, offs, outb, outb_bf);
  mlp1_mfma<<<N_NODES / 16, 256, 0, stream>>>(outb_bf, W1T, bm1, gm, bm, hb);
  mlp2_mfma<<<(N_NODES + 63) / 64, 256, 0, stream>>>(hb, W2T, bm2, outb, g2, b2, y);
}